// Round 1
// baseline (2453.059 us; speedup 1.0000x reference)
//
#include <hip/hip_runtime.h>
#include <cstdint>

// ---- JAX PRNG mode: 1 = jax_threefry_partitionable=True (jax >= 0.5 default),
//                     0 = original counter-mode threefry
#define JAX_PARTITIONABLE 1

constexpr int BATCH = 128;
constexpr int H = 512, W = 512;
constexpr int HW = H * W;       // 262144 = 2^18
constexpr int WPR = W / 64;     // 8 words per row
constexpr int WPI = HW / 64;    // 4096 words per image
constexpr int NSEED = 1000;

// ---------------- Threefry-2x32 (20 rounds), bit-exact vs JAX ----------------
__device__ __forceinline__ uint32_t rotl32(uint32_t v, int d) {
  return (v << d) | (v >> (32 - d));
}

__device__ __forceinline__ void tf2x32(uint32_t k0, uint32_t k1,
                                       uint32_t x0, uint32_t x1,
                                       uint32_t &o0, uint32_t &o1) {
  uint32_t ks2 = k0 ^ k1 ^ 0x1BD11BDAu;
  x0 += k0; x1 += k1;
  x0 += x1; x1 = rotl32(x1, 13); x1 ^= x0;
  x0 += x1; x1 = rotl32(x1, 15); x1 ^= x0;
  x0 += x1; x1 = rotl32(x1, 26); x1 ^= x0;
  x0 += x1; x1 = rotl32(x1, 6);  x1 ^= x0;
  x0 += k1; x1 += ks2 + 1u;
  x0 += x1; x1 = rotl32(x1, 17); x1 ^= x0;
  x0 += x1; x1 = rotl32(x1, 29); x1 ^= x0;
  x0 += x1; x1 = rotl32(x1, 16); x1 ^= x0;
  x0 += x1; x1 = rotl32(x1, 24); x1 ^= x0;
  x0 += ks2; x1 += k0 + 2u;
  x0 += x1; x1 = rotl32(x1, 13); x1 ^= x0;
  x0 += x1; x1 = rotl32(x1, 15); x1 ^= x0;
  x0 += x1; x1 = rotl32(x1, 26); x1 ^= x0;
  x0 += x1; x1 = rotl32(x1, 6);  x1 ^= x0;
  x0 += k0; x1 += k1 + 3u;
  x0 += x1; x1 = rotl32(x1, 17); x1 ^= x0;
  x0 += x1; x1 = rotl32(x1, 29); x1 ^= x0;
  x0 += x1; x1 = rotl32(x1, 16); x1 ^= x0;
  x0 += x1; x1 = rotl32(x1, 24); x1 ^= x0;
  x0 += k1; x1 += ks2 + 4u;
  x0 += x1; x1 = rotl32(x1, 13); x1 ^= x0;
  x0 += x1; x1 = rotl32(x1, 15); x1 ^= x0;
  x0 += x1; x1 = rotl32(x1, 26); x1 ^= x0;
  x0 += x1; x1 = rotl32(x1, 6);  x1 ^= x0;
  x0 += ks2; x1 += k0 + 5u;
  o0 = x0; o1 = x1;
}

// random bits for pixel i of a size-HW uniform draw
__device__ __forceinline__ uint32_t score_bits(uint32_t k0, uint32_t k1, uint32_t i) {
#if JAX_PARTITIONABLE
  uint32_t a, c; tf2x32(k0, k1, 0u, i, a, c);
  return a ^ c;   // 32-bit fold of the two outputs
#else
  uint32_t a, c;
  if (i < (uint32_t)(HW / 2)) { tf2x32(k0, k1, i, i + (uint32_t)(HW / 2), a, c); return a; }
  else                        { tf2x32(k0, k1, i - (uint32_t)(HW / 2), i, a, c); return c; }
#endif
}

// ------------- exact replica of jax.lax.associative_scan cumsum tree ---------
__device__ void tree_cumsum256(float* L, float* S) {
  const int off[9] = {0, 256, 384, 448, 480, 496, 504, 508, 510};
  const int sz[9]  = {256, 128, 64, 32, 16, 8, 4, 2, 1};
  for (int l = 0; l < 8; ++l) {
    int o = off[l], on = off[l + 1], n = sz[l + 1];
    for (int i = 0; i < n; ++i)
      L[on + i] = __fadd_rn(L[o + 2 * i], L[o + 2 * i + 1]);
  }
  S[off[8]] = L[off[8]];
  for (int l = 7; l >= 0; --l) {
    int o = off[l], on = off[l + 1], n = sz[l], h = n / 2;
    S[o] = L[o];
    for (int k = 0; k < h; ++k) S[o + 2 * k + 1] = S[on + k];
    for (int k = 1; k < h; ++k) S[o + 2 * k] = __fadd_rn(S[on + k - 1], L[o + 2 * k]);
  }
}

// ---------------- Kernel 1: histogram + Otsu + per-image keys ----------------
__global__ void k_hist_otsu(const float* __restrict__ x, int* __restrict__ th_out,
                            uint32_t* __restrict__ keys_out, uint32_t* __restrict__ kbg_out) {
  __shared__ uint32_t hist[256];
  __shared__ float Lt[511];
  __shared__ float St[511];
  __shared__ float wc[256];
  int b = blockIdx.x;
  int tid = threadIdx.x;
  if (tid < 256) hist[tid] = 0;
  __syncthreads();
  const float* xb = x + (size_t)b * HW;
  for (int p = tid; p < HW; p += blockDim.x) {
    float v = xb[p];
    int f = (int)floorf(__fmul_rn(v, 255.0f));
    f = min(max(f, 0), 255);
    atomicAdd(&hist[f], 1u);
  }
  __syncthreads();
  if (tid == 0) {
    for (int i = 0; i < 256; ++i) Lt[i] = (float)hist[i];
    tree_cumsum256(Lt, St);
    for (int i = 0; i < 256; ++i) wc[i] = St[i];
    for (int i = 0; i < 256; ++i) Lt[i] = __fmul_rn((float)hist[i], (float)i);
    tree_cumsum256(Lt, St);   // St[0..255] = m
    float total = (float)HW;
    float mT = St[255];
    float best = -1.0f; int bi = 0;
    for (int t = 0; t < 256; ++t) {
      float w = wc[t];
      float denom = __fmul_rn(w, __fsub_rn(total, w));
      float s = 0.0f;
      if (denom > 0.0f) {
        float d  = __fsub_rn(__fmul_rn(mT, w), __fmul_rn(total, St[t]));
        float nu = __fmul_rn(d, d);
        float dd = __fmul_rn(__fmul_rn(denom, total), total);
        s = __fdiv_rn(nu, dd);
      }
      if (s > best) { best = s; bi = t; }   // argmax, first occurrence
    }
    if (bi == 0) bi = 1;
    if (bi == 255) bi = 254;
    th_out[b] = bi;

    // per-image keys: root = key(42) = (0,42)
    uint32_t kf0, kf1, kB0, kB1, zb;
#if JAX_PARTITIONABLE
    uint32_t kb0, kb1; tf2x32(0u, 42u, 0u, (uint32_t)b, kb0, kb1);
    tf2x32(kb0, kb1, 0u, 0u, kf0, kf1);
    tf2x32(kb0, kb1, 0u, 1u, kB0, kB1);
    uint32_t kz0, kz1; tf2x32(kb0, kb1, 0u, 2u, kz0, kz1);
    uint32_t za, zc; tf2x32(kz0, kz1, 0u, 0u, za, zc); zb = za ^ zc;
#else
    uint32_t kb0, kb1;
    if (b < 64) {
      uint32_t a0, a1, c0, c1;
      tf2x32(0u, 42u, (uint32_t)(2 * b),     (uint32_t)(2 * b + 128), a0, a1);
      tf2x32(0u, 42u, (uint32_t)(2 * b + 1), (uint32_t)(2 * b + 129), c0, c1);
      kb0 = a0; kb1 = c0;
    } else {
      int c = 2 * b - 128;
      uint32_t a0, a1, d0, d1;
      tf2x32(0u, 42u, (uint32_t)c,       (uint32_t)(c + 128), a0, a1);
      tf2x32(0u, 42u, (uint32_t)(c + 1), (uint32_t)(c + 129), d0, d1);
      kb0 = a1; kb1 = d1;
    }
    uint32_t u0, w0, u1, w1, u2, w2;
    tf2x32(kb0, kb1, 0u, 3u, u0, w0);
    tf2x32(kb0, kb1, 1u, 4u, u1, w1);
    tf2x32(kb0, kb1, 2u, 5u, u2, w2);
    kf0 = u0; kf1 = u1; kB0 = u2; kB1 = w0;
    uint32_t kz0 = w1, kz1 = w2;
    uint32_t za, zc; tf2x32(kz0, kz1, 0u, 0u, za, zc); zb = za;
#endif
    keys_out[b * 4 + 0] = kf0; keys_out[b * 4 + 1] = kf1;
    keys_out[b * 4 + 2] = kB0; keys_out[b * 4 + 3] = kB1;
    float uu = __uint_as_float((zb >> 9) | 0x3f800000u) - 1.0f;  // exact
    float span = __fsub_rn(0.7f, 0.3f);
    float z = __fadd_rn(__fmul_rn(uu, span), 0.3f);
    z = fmaxf(0.3f, z);
    float nb = ceilf(__fmul_rn(z, (float)HW));
    kbg_out[b] = (uint32_t)nb;
  }
}

// ---------------- ROI bitmap: bit = floor(x*255) > th --------------------
__global__ void k_roi(const float* __restrict__ x, const int* __restrict__ th,
                      uint64_t* __restrict__ roi) {
  int p = blockIdx.x * blockDim.x + threadIdx.x;
  int b = p >> 18;
  float v = x[p];
  int f = (int)floorf(__fmul_rn(v, 255.0f));
  bool pred = f > th[b];
  uint64_t bw = __ballot(pred);
  if ((threadIdx.x & 63) == 0) roi[p >> 6] = bw;
}

// ---------- erosion: 11-wide row min (OOB = 1), then 11-tall col min --------
__global__ void k_rowmin(const uint64_t* __restrict__ in, uint64_t* __restrict__ out) {
  int w = blockIdx.x * blockDim.x + threadIdx.x;
  int c = w & (WPR - 1);
  uint64_t cur = in[w];
  uint64_t left  = (c > 0)       ? in[w - 1] : ~0ull;
  uint64_t right = (c < WPR - 1) ? in[w + 1] : ~0ull;
  uint64_t res = cur;
#pragma unroll
  for (int s = 1; s <= 5; ++s) {
    res &= (cur >> s) | (right << (64 - s));
    res &= (cur << s) | (left >> (64 - s));
  }
  out[w] = res;
}

__global__ void k_colmin(const uint64_t* __restrict__ in, uint64_t* __restrict__ out) {
  int w = blockIdx.x * blockDim.x + threadIdx.x;
  int wi = w & (WPI - 1);
  int r = wi >> 3;
  uint64_t res = in[w];
#pragma unroll
  for (int d = 1; d <= 5; ++d) {
    if (r >= d)     res &= in[w - WPR * d];
    if (r + d < H)  res &= in[w + WPR * d];
  }
  out[w] = res;
}

// -------- top-1000 select among eligible by (scorebits desc, idx asc) -------
__global__ __launch_bounds__(1024) void k_select(const uint64_t* __restrict__ elig,
                                                 const uint32_t* __restrict__ keys, int key_off,
                                                 uint64_t* __restrict__ om_all) {
  __shared__ uint32_t hist[4096];
  __shared__ uint32_t tie[2048];
  __shared__ uint32_t sE, tcnt;
  __shared__ uint32_t sb1, sr1, svstar, sr2, sidxcut;
  int b = blockIdx.x, tid = threadIdx.x;
  const uint64_t* eb = elig + (size_t)b * WPI;
  uint64_t* om = om_all + (size_t)b * WPI;
  uint32_t k0 = keys[b * 4 + key_off], k1 = keys[b * 4 + key_off + 1];
  if (tid == 0) sE = 0;
  __syncthreads();
  uint32_t loc = 0;
  for (int w = tid; w < WPI; w += blockDim.x) loc += (uint32_t)__popcll(eb[w]);
  atomicAdd(&sE, loc);
  __syncthreads();
  uint32_t E = sE;
  if (E <= (uint32_t)NSEED) {  // take all eligible (matches vals > -inf filter)
    for (int w = tid; w < WPI; w += blockDim.x) om[w] = eb[w];
    return;
  }
  // L1: hist over v>>11 (v = bits>>9, 23 bits)
  for (int i = tid; i < 4096; i += blockDim.x) hist[i] = 0;
  __syncthreads();
  for (int p = tid; p < HW; p += blockDim.x) {
    uint64_t wv = eb[p >> 6];
    if ((wv >> (p & 63)) & 1ull) {
      uint32_t v = score_bits(k0, k1, (uint32_t)p) >> 9;
      atomicAdd(&hist[v >> 11], 1u);
    }
  }
  __syncthreads();
  if (tid == 0) {
    uint32_t acc = 0;
    for (int bin = 4095; bin >= 0; --bin) {
      uint32_t c = hist[bin];
      if (acc + c >= (uint32_t)NSEED) { sb1 = (uint32_t)bin; sr1 = (uint32_t)NSEED - acc; break; }
      acc += c;
    }
  }
  __syncthreads();
  uint32_t b1 = sb1, r1 = sr1;
  // L2: hist over v & 0x7FF within bin b1
  for (int i = tid; i < 4096; i += blockDim.x) hist[i] = 0;
  __syncthreads();
  for (int p = tid; p < HW; p += blockDim.x) {
    uint64_t wv = eb[p >> 6];
    if ((wv >> (p & 63)) & 1ull) {
      uint32_t v = score_bits(k0, k1, (uint32_t)p) >> 9;
      if ((v >> 11) == b1) atomicAdd(&hist[v & 0x7FFu], 1u);
    }
  }
  __syncthreads();
  if (tid == 0) {
    uint32_t acc = 0;
    for (int bin = 2047; bin >= 0; --bin) {
      uint32_t c = hist[bin];
      if (acc + c >= r1) { svstar = (b1 << 11) | (uint32_t)bin; sr2 = r1 - acc; break; }
      acc += c;
    }
    tcnt = 0;
  }
  __syncthreads();
  uint32_t vstar = svstar, r2 = sr2;
  // exact-tie collection: eligible pixels with v == vstar, pick r2 smallest idx
  for (int p = tid; p < HW; p += blockDim.x) {
    uint64_t wv = eb[p >> 6];
    if ((wv >> (p & 63)) & 1ull) {
      uint32_t v = score_bits(k0, k1, (uint32_t)p) >> 9;
      if (v == vstar) {
        uint32_t pos = atomicAdd(&tcnt, 1u);
        if (pos < 2048u) tie[pos] = (uint32_t)p;
      }
    }
  }
  __syncthreads();
  if (tid == 0) {
    int m = (int)min(tcnt, 2048u);
    for (int i = 1; i < m; ++i) {
      uint32_t kv = tie[i]; int j = i - 1;
      while (j >= 0 && tie[j] > kv) { tie[j + 1] = tie[j]; --j; }
      tie[j + 1] = kv;
    }
    int pick = min((int)r2, m) - 1; if (pick < 0) pick = 0;
    sidxcut = tie[pick];
  }
  __syncthreads();
  uint32_t idxcut = sidxcut;
  // emit selection bitmap via wave ballot
  int wave = tid >> 6, lane = tid & 63;
  int nw = blockDim.x >> 6;
  for (int w = wave; w < WPI; w += nw) {
    uint64_t wv = eb[w];
    int p = (w << 6) | lane;
    bool sel = false;
    if ((wv >> lane) & 1ull) {
      uint32_t v = score_bits(k0, k1, (uint32_t)p) >> 9;
      sel = (v > vstar) || (v == vstar && (uint32_t)p <= idxcut);
    }
    uint64_t bw = __ballot(sel);
    if (lane == 0) om[w] = bw;
  }
}

// ---- bg eligibility: bottom-K by (float-bit-pattern asc, idx asc) ----------
__global__ __launch_bounds__(1024) void k_bgelig(const float* __restrict__ x,
                                                 const uint32_t* __restrict__ kbg,
                                                 uint64_t* __restrict__ elig_all) {
  __shared__ uint32_t hist[4096];
  __shared__ uint32_t tie[2048];
  __shared__ uint32_t tcnt;
  __shared__ uint32_t sb1, sr1, spre24, sr2, sPstar, sidxcut;
  int b = blockIdx.x, tid = threadIdx.x;
  const float* xb = x + (size_t)b * HW;
  uint64_t* el = elig_all + (size_t)b * WPI;
  uint32_t K = kbg[b];
  for (int i = tid; i < 4096; i += blockDim.x) hist[i] = 0;
  __syncthreads();
  for (int p = tid; p < HW; p += blockDim.x) {
    uint32_t pat = __float_as_uint(xb[p]);
    atomicAdd(&hist[pat >> 20], 1u);
  }
  __syncthreads();
  if (tid == 0) {
    uint32_t acc = 0;
    for (int bin = 0; bin < 4096; ++bin) {
      uint32_t c = hist[bin];
      if (acc + c >= K) { sb1 = (uint32_t)bin; sr1 = K - acc; break; }
      acc += c;
    }
  }
  __syncthreads();
  uint32_t b1 = sb1, r1 = sr1;
  for (int i = tid; i < 4096; i += blockDim.x) hist[i] = 0;
  __syncthreads();
  for (int p = tid; p < HW; p += blockDim.x) {
    uint32_t pat = __float_as_uint(xb[p]);
    if ((pat >> 20) == b1) atomicAdd(&hist[(pat >> 8) & 0xFFFu], 1u);
  }
  __syncthreads();
  if (tid == 0) {
    uint32_t acc = 0;
    for (int bin = 0; bin < 4096; ++bin) {
      uint32_t c = hist[bin];
      if (acc + c >= r1) { spre24 = (b1 << 12) | (uint32_t)bin; sr2 = r1 - acc; break; }
      acc += c;
    }
    tcnt = 0;
  }
  __syncthreads();
  uint32_t pre24 = spre24, r2 = sr2;
  for (int p = tid; p < HW; p += blockDim.x) {
    uint32_t pat = __float_as_uint(xb[p]);
    if ((pat >> 8) == pre24) {
      uint32_t pos = atomicAdd(&tcnt, 1u);
      if (pos < 2048u) tie[pos] = ((pat & 0xFFu) << 18) | (uint32_t)p;  // (low8, idx) asc
    }
  }
  __syncthreads();
  if (tid == 0) {
    int m = (int)min(tcnt, 2048u);
    for (int i = 1; i < m; ++i) {
      uint32_t kv = tie[i]; int j = i - 1;
      while (j >= 0 && tie[j] > kv) { tie[j + 1] = tie[j]; --j; }
      tie[j + 1] = kv;
    }
    int pick = min((int)r2, m) - 1; if (pick < 0) pick = 0;
    uint32_t cut = tie[pick];
    sPstar = (pre24 << 8) | (cut >> 18);
    sidxcut = cut & 0x3FFFFu;
  }
  __syncthreads();
  uint32_t Pstar = sPstar, idxcut = sidxcut;
  int wave = tid >> 6, lane = tid & 63;
  int nw = blockDim.x >> 6;
  for (int w = wave; w < WPI; w += nw) {
    int p = (w << 6) | lane;
    uint32_t pat = __float_as_uint(xb[p]);
    bool e2 = (pat < Pstar) || (pat == Pstar && (uint32_t)p <= idxcut);
    uint64_t bw = __ballot(e2);
    if (lane == 0) el[w] = bw;
  }
}

// -------- 3-wide row dilation (OR, OOB = 0) --------
__global__ void k_rowdil(const uint64_t* __restrict__ in, uint64_t* __restrict__ out) {
  int w = blockIdx.x * blockDim.x + threadIdx.x;
  int c = w & (WPR - 1);
  uint64_t cur = in[w];
  uint64_t left  = (c > 0)       ? in[w - 1] : 0ull;
  uint64_t right = (c < WPR - 1) ? in[w + 1] : 0ull;
  out[w] = cur | (cur << 1) | (left >> 63) | (cur >> 1) | (right << 63);
}

// -------- column dilation + overlap removal + compose --------
__global__ void k_compose(const uint64_t* __restrict__ fgrow, const uint64_t* __restrict__ bgrow,
                          int* __restrict__ out) {
  int p = blockIdx.x * blockDim.x + threadIdx.x;
  int q = p & (HW - 1);
  int r = q >> 9;
  int gw = p >> 6;
  uint64_t F = fgrow[gw], Bb = bgrow[gw];
  if (r > 0)     { F |= fgrow[gw - WPR]; Bb |= bgrow[gw - WPR]; }
  if (r < H - 1) { F |= fgrow[gw + WPR]; Bb |= bgrow[gw + WPR]; }
  uint64_t ov = F & Bb;
  F &= ~ov; Bb &= ~ov;
  int lane = p & 63;
  int val = ((F >> lane) & 1ull) ? 1 : (((Bb >> lane) & 1ull) ? 0 : -255);
  out[p] = val;
}

extern "C" void kernel_launch(void* const* d_in, const int* in_sizes, int n_in,
                              void* d_out, int out_size, void* d_ws, size_t ws_size,
                              hipStream_t stream) {
  (void)in_sizes; (void)n_in; (void)out_size; (void)ws_size;
  const float* x = (const float*)d_in[0];
  int* out = (int*)d_out;
  char* ws = (char*)d_ws;
  int* th        = (int*)ws;                     // 128 * 4 B
  uint32_t* keys = (uint32_t*)(ws + 512);        // 128 * 4 u32 (kf0,kf1,kb0,kb1)
  uint32_t* kbg  = (uint32_t*)(ws + 2560);       // 128 * 4 B
  uint64_t* bufA = (uint64_t*)(ws + 4096);       // 3 bitmap buffers, 4 MB each
  uint64_t* bufB = bufA + (size_t)BATCH * WPI;
  uint64_t* bufC = bufB + (size_t)BATCH * WPI;

  k_hist_otsu<<<BATCH, 256, 0, stream>>>(x, th, keys, kbg);
  k_roi    <<<(BATCH * HW) / 256, 256, 0, stream>>>(x, th, bufA);
  k_rowmin <<<(BATCH * WPI) / 256, 256, 0, stream>>>(bufA, bufB);
  k_colmin <<<(BATCH * WPI) / 256, 256, 0, stream>>>(bufB, bufA);   // eroded in A
  k_select <<<BATCH, 1024, 0, stream>>>(bufA, keys, 0, bufB);       // fg in B
  k_bgelig <<<BATCH, 1024, 0, stream>>>(x, kbg, bufC);              // elig in C
  k_select <<<BATCH, 1024, 0, stream>>>(bufC, keys, 2, bufA);       // bg in A
  k_rowdil <<<(BATCH * WPI) / 256, 256, 0, stream>>>(bufB, bufC);   // fg row-dil in C
  k_rowdil <<<(BATCH * WPI) / 256, 256, 0, stream>>>(bufA, bufB);   // bg row-dil in B
  k_compose<<<(BATCH * HW) / 256, 256, 0, stream>>>(bufC, bufB, out);
}

// Round 2
// 2176.021 us; speedup vs baseline: 1.1273x; 1.1273x over previous
//
#include <hip/hip_runtime.h>
#include <cstdint>

constexpr int BATCH = 128;
constexpr int H = 512, W = 512;
constexpr int HW = H * W;       // 2^18
constexpr int WPR = W / 64;     // 8 words per row
constexpr int WPI = HW / 64;    // 4096 words per image
constexpr int NSEED = 1000;
constexpr int CAP = 1024;       // per-image tie-bin list capacity (expected ~64)

// ---------------- Threefry-2x32 (20 rounds), bit-exact vs JAX ----------------
__device__ __forceinline__ uint32_t rotl32(uint32_t v, int d) {
  return (v << d) | (v >> (32 - d));
}

__device__ __forceinline__ void tf2x32(uint32_t k0, uint32_t k1,
                                       uint32_t x0, uint32_t x1,
                                       uint32_t &o0, uint32_t &o1) {
  uint32_t ks2 = k0 ^ k1 ^ 0x1BD11BDAu;
  x0 += k0; x1 += k1;
  x0 += x1; x1 = rotl32(x1, 13); x1 ^= x0;
  x0 += x1; x1 = rotl32(x1, 15); x1 ^= x0;
  x0 += x1; x1 = rotl32(x1, 26); x1 ^= x0;
  x0 += x1; x1 = rotl32(x1, 6);  x1 ^= x0;
  x0 += k1; x1 += ks2 + 1u;
  x0 += x1; x1 = rotl32(x1, 17); x1 ^= x0;
  x0 += x1; x1 = rotl32(x1, 29); x1 ^= x0;
  x0 += x1; x1 = rotl32(x1, 16); x1 ^= x0;
  x0 += x1; x1 = rotl32(x1, 24); x1 ^= x0;
  x0 += ks2; x1 += k0 + 2u;
  x0 += x1; x1 = rotl32(x1, 13); x1 ^= x0;
  x0 += x1; x1 = rotl32(x1, 15); x1 ^= x0;
  x0 += x1; x1 = rotl32(x1, 26); x1 ^= x0;
  x0 += x1; x1 = rotl32(x1, 6);  x1 ^= x0;
  x0 += k0; x1 += k1 + 3u;
  x0 += x1; x1 = rotl32(x1, 17); x1 ^= x0;
  x0 += x1; x1 = rotl32(x1, 29); x1 ^= x0;
  x0 += x1; x1 = rotl32(x1, 16); x1 ^= x0;
  x0 += x1; x1 = rotl32(x1, 24); x1 ^= x0;
  x0 += k1; x1 += ks2 + 4u;
  x0 += x1; x1 = rotl32(x1, 13); x1 ^= x0;
  x0 += x1; x1 = rotl32(x1, 15); x1 ^= x0;
  x0 += x1; x1 = rotl32(x1, 26); x1 ^= x0;
  x0 += x1; x1 = rotl32(x1, 6);  x1 ^= x0;
  x0 += ks2; x1 += k0 + 5u;
  o0 = x0; o1 = x1;
}

// random bits for pixel i of a size-HW uniform draw (partitionable threefry)
__device__ __forceinline__ uint32_t score_bits(uint32_t k0, uint32_t k1, uint32_t i) {
  uint32_t a, c; tf2x32(k0, k1, 0u, i, a, c);
  return a ^ c;
}

// ------------- exact replica of jax.lax.associative_scan cumsum tree ---------
__device__ void tree_cumsum256(float* L, float* S) {
  const int off[9] = {0, 256, 384, 448, 480, 496, 504, 508, 510};
  const int sz[9]  = {256, 128, 64, 32, 16, 8, 4, 2, 1};
  for (int l = 0; l < 8; ++l) {
    int o = off[l], on = off[l + 1], n = sz[l + 1];
    for (int i = 0; i < n; ++i)
      L[on + i] = __fadd_rn(L[o + 2 * i], L[o + 2 * i + 1]);
  }
  S[off[8]] = L[off[8]];
  for (int l = 7; l >= 0; --l) {
    int o = off[l], on = off[l + 1], n = sz[l], h = n / 2;
    S[o] = L[o];
    for (int k = 0; k < h; ++k) S[o + 2 * k + 1] = S[on + k];
    for (int k = 1; k < h; ++k) S[o + 2 * k] = __fadd_rn(S[on + k - 1], L[o + 2 * k]);
  }
}

// ---------------- per-image keys + nbr_bg ----------------
__global__ void k_keys(uint32_t* __restrict__ keys, uint32_t* __restrict__ kbg) {
  int b = threadIdx.x;
  if (b >= BATCH) return;
  uint32_t kb0, kb1; tf2x32(0u, 42u, 0u, (uint32_t)b, kb0, kb1);
  uint32_t kf0, kf1; tf2x32(kb0, kb1, 0u, 0u, kf0, kf1);
  uint32_t kB0, kB1; tf2x32(kb0, kb1, 0u, 1u, kB0, kB1);
  uint32_t kz0, kz1; tf2x32(kb0, kb1, 0u, 2u, kz0, kz1);
  uint32_t za, zc; tf2x32(kz0, kz1, 0u, 0u, za, zc);
  uint32_t zb = za ^ zc;
  keys[b * 4 + 0] = kf0; keys[b * 4 + 1] = kf1;
  keys[b * 4 + 2] = kB0; keys[b * 4 + 3] = kB1;
  float uu = __uint_as_float((zb >> 9) | 0x3f800000u) - 1.0f;
  float span = __fsub_rn(0.7f, 0.3f);
  float z = __fadd_rn(__fmul_rn(uu, span), 0.3f);
  z = fmaxf(0.3f, z);
  float nb = ceilf(__fmul_rn(z, (float)HW));
  kbg[b] = (uint32_t)nb;
}

// ---------------- grid-wide 256-bin histogram ----------------
__global__ void k_hist256(const float* __restrict__ x, uint32_t* __restrict__ gh) {
  __shared__ uint32_t h[256];
  int b = blockIdx.x >> 4, sub = blockIdx.x & 15;
  int tid = threadIdx.x;
  h[tid] = 0;
  __syncthreads();
  const float* xb = x + (size_t)b * HW + sub * (HW / 16);
  for (int i = tid; i < HW / 16; i += 256) {
    float v = xb[i];
    int f = (int)floorf(__fmul_rn(v, 255.0f));
    f = min(max(f, 0), 255);
    atomicAdd(&h[f], 1u);
  }
  __syncthreads();
  if (h[tid]) atomicAdd(&gh[b * 256 + tid], h[tid]);
}

// ---------------- Otsu from histogram (1 thread per image) ----------------
__global__ void k_otsu(const uint32_t* __restrict__ gh, int* __restrict__ th_out) {
  int b = blockIdx.x * blockDim.x + threadIdx.x;
  if (b >= BATCH) return;
  float Lt[511], St[511], wc[256];
  const uint32_t* hist = gh + (size_t)b * 256;
  for (int i = 0; i < 256; ++i) Lt[i] = (float)hist[i];
  tree_cumsum256(Lt, St);
  for (int i = 0; i < 256; ++i) wc[i] = St[i];
  for (int i = 0; i < 256; ++i) Lt[i] = __fmul_rn((float)hist[i], (float)i);
  tree_cumsum256(Lt, St);   // St = m
  float total = (float)HW;
  float mT = St[255];
  float best = -1.0f; int bi = 0;
  for (int t = 0; t < 256; ++t) {
    float w = wc[t];
    float denom = __fmul_rn(w, __fsub_rn(total, w));
    float s = 0.0f;
    if (denom > 0.0f) {
      float d  = __fsub_rn(__fmul_rn(mT, w), __fmul_rn(total, St[t]));
      float nu = __fmul_rn(d, d);
      float dd = __fmul_rn(__fmul_rn(denom, total), total);
      s = __fdiv_rn(nu, dd);
    }
    if (s > best) { best = s; bi = t; }
  }
  if (bi == 0) bi = 1;
  if (bi == 255) bi = 254;
  th_out[b] = bi;
}

// ---------------- ROI bitmap: bit = floor(x*255) > th --------------------
__global__ void k_roi(const float* __restrict__ x, const int* __restrict__ th,
                      uint64_t* __restrict__ roi) {
  int p = blockIdx.x * blockDim.x + threadIdx.x;
  int b = p >> 18;
  float v = x[p];
  int f = (int)floorf(__fmul_rn(v, 255.0f));
  bool pred = f > th[b];
  uint64_t bw = __ballot(pred);
  if ((threadIdx.x & 63) == 0) roi[p >> 6] = bw;
}

// ---------- erosion: 11-wide row min (OOB = 1), then 11-tall col min --------
__global__ void k_rowmin(const uint64_t* __restrict__ in, uint64_t* __restrict__ out) {
  int w = blockIdx.x * blockDim.x + threadIdx.x;
  int c = w & (WPR - 1);
  uint64_t cur = in[w];
  uint64_t left  = (c > 0)       ? in[w - 1] : ~0ull;
  uint64_t right = (c < WPR - 1) ? in[w + 1] : ~0ull;
  uint64_t res = cur;
#pragma unroll
  for (int s = 1; s <= 5; ++s) {
    res &= (cur >> s) | (right << (64 - s));
    res &= (cur << s) | (left >> (64 - s));
  }
  out[w] = res;
}

__global__ void k_colmin(const uint64_t* __restrict__ in, uint64_t* __restrict__ out) {
  int w = blockIdx.x * blockDim.x + threadIdx.x;
  int wi = w & (WPI - 1);
  int r = wi >> 3;
  uint64_t res = in[w];
#pragma unroll
  for (int d = 1; d <= 5; ++d) {
    if (r >= d)     res &= in[w - WPR * d];
    if (r + d < H)  res &= in[w + WPR * d];
  }
  out[w] = res;
}

// ---------------- per-image popcount of a bitmap ----------------
__global__ void k_count(const uint64_t* __restrict__ bm, uint32_t* __restrict__ E) {
  int b = blockIdx.x, tid = threadIdx.x;
  uint32_t loc = 0;
  for (int w = tid; w < WPI; w += blockDim.x) loc += (uint32_t)__popcll(bm[(size_t)b * WPI + w]);
  atomicAdd(&E[b], loc);
}

// ============ generic top-NSEED-by-random-score select (grid-wide) ============
// bins: v = score>>9 (23 bits); L1 bin = v>>11 (4096 bins, scanned descending)
__global__ __launch_bounds__(1024) void k_sel_hist(const uint64_t* __restrict__ elig,
                                                   const uint32_t* __restrict__ keys, int koff,
                                                   const uint32_t* __restrict__ E,
                                                   uint32_t* __restrict__ gh) {
  int b = blockIdx.x >> 2, sub = blockIdx.x & 3;
  if (E[b] <= (uint32_t)NSEED) return;
  __shared__ uint32_t h[4096];
  int tid = threadIdx.x;
  for (int i = tid; i < 4096; i += 1024) h[i] = 0;
  __syncthreads();
  uint32_t k0 = keys[b * 4 + koff], k1 = keys[b * 4 + koff + 1];
  const uint64_t* eb = elig + (size_t)b * WPI;
  int base = sub * (HW / 4);
  for (int i = tid; i < HW / 4; i += 1024) {
    int p = base + i;
    if ((eb[p >> 6] >> (p & 63)) & 1ull) {
      uint32_t v = score_bits(k0, k1, (uint32_t)p) >> 9;
      atomicAdd(&h[v >> 11], 1u);
    }
  }
  __syncthreads();
  for (int i = tid; i < 4096; i += 1024)
    if (h[i]) atomicAdd(&gh[(size_t)b * 4096 + i], h[i]);
}

__global__ void k_sel_scan(const uint32_t* __restrict__ gh, const uint32_t* __restrict__ E,
                           uint32_t* __restrict__ b1a, uint32_t* __restrict__ r1a) {
  int b = blockIdx.x * blockDim.x + threadIdx.x;
  if (b >= BATCH) return;
  if (E[b] <= (uint32_t)NSEED) { b1a[b] = 0xFFFFFFFFu; r1a[b] = 0; return; }
  const uint32_t* h = gh + (size_t)b * 4096;
  uint32_t acc = 0, b1 = 0, r1 = 1;
  for (int bin = 4095; bin >= 0; --bin) {
    uint32_t c = h[bin];
    if (acc + c >= (uint32_t)NSEED) { b1 = (uint32_t)bin; r1 = (uint32_t)NSEED - acc; break; }
    acc += c;
  }
  b1a[b] = b1; r1a[b] = r1;
}

__global__ __launch_bounds__(1024) void k_sel_collect(const uint64_t* __restrict__ elig,
                                                      const uint32_t* __restrict__ keys, int koff,
                                                      const uint32_t* __restrict__ b1a,
                                                      uint32_t* __restrict__ cnt,
                                                      uint64_t* __restrict__ list) {
  int b = blockIdx.x >> 2, sub = blockIdx.x & 3;
  uint32_t b1 = b1a[b];
  if (b1 == 0xFFFFFFFFu) return;
  uint32_t k0 = keys[b * 4 + koff], k1 = keys[b * 4 + koff + 1];
  const uint64_t* eb = elig + (size_t)b * WPI;
  int tid = threadIdx.x;
  int base = sub * (HW / 4);
  for (int i = tid; i < HW / 4; i += 1024) {
    int p = base + i;
    if ((eb[p >> 6] >> (p & 63)) & 1ull) {
      uint32_t v = score_bits(k0, k1, (uint32_t)p) >> 9;
      if ((v >> 11) == b1) {
        uint32_t pos = atomicAdd(&cnt[b], 1u);
        if (pos < (uint32_t)CAP)
          list[(size_t)b * CAP + pos] = (((uint64_t)((~v) & 0x7FFFFFu)) << 18) | (uint32_t)p;
      }
    }
  }
}

// shared by score-select and float-select: sort tie list, pick r1-th key
__global__ void k_cut(const uint32_t* __restrict__ b1a, const uint32_t* __restrict__ r1a,
                      const uint32_t* __restrict__ cnt, const uint64_t* __restrict__ list,
                      uint64_t* __restrict__ cut) {
  int b = blockIdx.x * blockDim.x + threadIdx.x;
  if (b >= BATCH) return;
  if (b1a[b] == 0xFFFFFFFFu) { cut[b] = ~0ull; return; }
  int n = min((int)cnt[b], CAP);
  if (n == 0) { cut[b] = 0; return; }
  uint64_t loc[CAP];
  const uint64_t* lb = list + (size_t)b * CAP;
  for (int i = 0; i < n; ++i) loc[i] = lb[i];
  for (int i = 1; i < n; ++i) {
    uint64_t kv = loc[i]; int j = i - 1;
    while (j >= 0 && loc[j] > kv) { loc[j + 1] = loc[j]; --j; }
    loc[j + 1] = kv;
  }
  int r = (int)r1a[b]; if (r > n) r = n; if (r < 1) r = 1;
  cut[b] = loc[r - 1];
}

__global__ __launch_bounds__(1024) void k_sel_emit(const uint64_t* __restrict__ elig,
                                                   const uint32_t* __restrict__ keys, int koff,
                                                   const uint64_t* __restrict__ cut,
                                                   uint64_t* __restrict__ out) {
  int b = blockIdx.x >> 2, sub = blockIdx.x & 3;
  uint32_t k0 = keys[b * 4 + koff], k1 = keys[b * 4 + koff + 1];
  uint64_t cutkey = cut[b];
  const uint64_t* eb = elig + (size_t)b * WPI;
  int tid = threadIdx.x;
  int wave = tid >> 6, lane = tid & 63;
  for (int wl = wave; wl < WPI / 4; wl += 16) {
    int w = sub * (WPI / 4) + wl;
    uint64_t ew = eb[w];
    int p = (w << 6) | lane;
    bool sel = false;
    if ((ew >> lane) & 1ull) {
      uint32_t v = score_bits(k0, k1, (uint32_t)p) >> 9;
      uint64_t key = (((uint64_t)((~v) & 0x7FFFFFu)) << 18) | (uint32_t)p;
      sel = key <= cutkey;
    }
    uint64_t bw = __ballot(sel);
    if (lane == 0) out[(size_t)b * WPI + w] = bw;
  }
}

// ============ bg eligibility: bottom-K by (float asc, idx asc), grid-wide =====
__global__ __launch_bounds__(1024) void k_bg_hist(const float* __restrict__ x,
                                                  uint32_t* __restrict__ gh) {
  int b = blockIdx.x >> 2, sub = blockIdx.x & 3;
  __shared__ uint32_t h[4096];
  int tid = threadIdx.x;
  for (int i = tid; i < 4096; i += 1024) h[i] = 0;
  __syncthreads();
  const float* xb = x + (size_t)b * HW + sub * (HW / 4);
  for (int i = tid; i < HW / 4; i += 1024) {
    int bin = (int)floorf(__fmul_rn(xb[i], 4096.0f));
    bin = min(max(bin, 0), 4095);
    atomicAdd(&h[bin], 1u);
  }
  __syncthreads();
  for (int i = tid; i < 4096; i += 1024)
    if (h[i]) atomicAdd(&gh[(size_t)b * 4096 + i], h[i]);
}

__global__ void k_bg_scan(const uint32_t* __restrict__ gh, const uint32_t* __restrict__ kbg,
                          uint32_t* __restrict__ b1a, uint32_t* __restrict__ r1a) {
  int b = blockIdx.x * blockDim.x + threadIdx.x;
  if (b >= BATCH) return;
  uint32_t K = kbg[b];
  const uint32_t* h = gh + (size_t)b * 4096;
  uint32_t acc = 0, b1 = 0, r1 = 1;
  for (int bin = 0; bin < 4096; ++bin) {
    uint32_t c = h[bin];
    if (acc + c >= K) { b1 = (uint32_t)bin; r1 = K - acc; break; }
    acc += c;
  }
  b1a[b] = b1; r1a[b] = r1;
}

__global__ __launch_bounds__(1024) void k_bg_collect(const float* __restrict__ x,
                                                     const uint32_t* __restrict__ b1a,
                                                     uint32_t* __restrict__ cnt,
                                                     uint64_t* __restrict__ list) {
  int b = blockIdx.x >> 2, sub = blockIdx.x & 3;
  uint32_t b1 = b1a[b];
  const float* xb = x + (size_t)b * HW;
  int tid = threadIdx.x;
  int base = sub * (HW / 4);
  for (int i = tid; i < HW / 4; i += 1024) {
    int p = base + i;
    float v = xb[p];
    int bin = (int)floorf(__fmul_rn(v, 4096.0f));
    bin = min(max(bin, 0), 4095);
    if ((uint32_t)bin == b1) {
      uint32_t pos = atomicAdd(&cnt[b], 1u);
      if (pos < (uint32_t)CAP)
        list[(size_t)b * CAP + pos] = (((uint64_t)__float_as_uint(v)) << 18) | (uint32_t)p;
    }
  }
}

__global__ __launch_bounds__(1024) void k_bg_emit(const float* __restrict__ x,
                                                  const uint64_t* __restrict__ cut,
                                                  uint64_t* __restrict__ out) {
  int b = blockIdx.x >> 2, sub = blockIdx.x & 3;
  uint64_t cutkey = cut[b];
  const float* xb = x + (size_t)b * HW;
  int tid = threadIdx.x;
  int wave = tid >> 6, lane = tid & 63;
  for (int wl = wave; wl < WPI / 4; wl += 16) {
    int w = sub * (WPI / 4) + wl;
    int p = (w << 6) | lane;
    uint64_t key = (((uint64_t)__float_as_uint(xb[p])) << 18) | (uint32_t)p;
    bool sel = key <= cutkey;
    uint64_t bw = __ballot(sel);
    if (lane == 0) out[(size_t)b * WPI + w] = bw;
  }
}

// -------- 3-wide row dilation (OR, OOB = 0) --------
__global__ void k_rowdil(const uint64_t* __restrict__ in, uint64_t* __restrict__ out) {
  int w = blockIdx.x * blockDim.x + threadIdx.x;
  int c = w & (WPR - 1);
  uint64_t cur = in[w];
  uint64_t left  = (c > 0)       ? in[w - 1] : 0ull;
  uint64_t right = (c < WPR - 1) ? in[w + 1] : 0ull;
  out[w] = cur | (cur << 1) | (left >> 63) | (cur >> 1) | (right << 63);
}

// -------- column dilation + overlap removal + compose --------
__global__ void k_compose(const uint64_t* __restrict__ fgrow, const uint64_t* __restrict__ bgrow,
                          int* __restrict__ out) {
  int p = blockIdx.x * blockDim.x + threadIdx.x;
  int q = p & (HW - 1);
  int r = q >> 9;
  int gw = p >> 6;
  uint64_t F = fgrow[gw], Bb = bgrow[gw];
  if (r > 0)     { F |= fgrow[gw - WPR]; Bb |= bgrow[gw - WPR]; }
  if (r < H - 1) { F |= fgrow[gw + WPR]; Bb |= bgrow[gw + WPR]; }
  uint64_t ov = F & Bb;
  F &= ~ov; Bb &= ~ov;
  int lane = p & 63;
  int val = ((F >> lane) & 1ull) ? 1 : (((Bb >> lane) & 1ull) ? 0 : -255);
  out[p] = val;
}

extern "C" void kernel_launch(void* const* d_in, const int* in_sizes, int n_in,
                              void* d_out, int out_size, void* d_ws, size_t ws_size,
                              hipStream_t stream) {
  (void)in_sizes; (void)n_in; (void)out_size; (void)ws_size;
  const float* x = (const float*)d_in[0];
  int* out = (int*)d_out;
  char* ws = (char*)d_ws;

  // ---- workspace layout (bytes) ----
  uint32_t* keys  = (uint32_t*)(ws + 0);        // 128*4 u32
  uint32_t* kbg   = (uint32_t*)(ws + 2048);     // 128
  int*      th    = (int*)     (ws + 2560);     // 128
  uint32_t* b1_fg = (uint32_t*)(ws + 3072);
  uint32_t* r1_fg = (uint32_t*)(ws + 3584);
  uint32_t* b1_bg = (uint32_t*)(ws + 4096);
  uint32_t* r1_bg = (uint32_t*)(ws + 4608);
  uint32_t* b1_be = (uint32_t*)(ws + 5120);
  uint32_t* r1_be = (uint32_t*)(ws + 5632);
  uint64_t* cut_fg = (uint64_t*)(ws + 6144);    // 128 u64
  uint64_t* cut_bg = (uint64_t*)(ws + 7168);
  uint64_t* cut_be = (uint64_t*)(ws + 8192);
  // zeroed region [16384, 16384+6424576)
  char* Z = ws + 16384;
  uint32_t* Efg    = (uint32_t*)(Z + 0);        // 512 B
  uint32_t* cnt_fg = (uint32_t*)(Z + 512);
  uint32_t* cnt_bg = (uint32_t*)(Z + 1024);
  uint32_t* cnt_be = (uint32_t*)(Z + 1536);
  uint32_t* gh256  = (uint32_t*)(Z + 2048);     // 128*256*4 = 131072
  uint32_t* gh_fg  = (uint32_t*)(Z + 133120);   // 128*4096*4 = 2 MB
  uint32_t* gh_bg  = (uint32_t*)(Z + 2230272);
  uint32_t* gh_be  = (uint32_t*)(Z + 4327424);
  size_t Zsize = 4327424 + 2097152;             // = 6424576
  char* P = Z + Zsize;
  uint64_t* list_fg = (uint64_t*)(P + 0);       // 128*CAP*8 = 1 MB
  uint64_t* list_bg = (uint64_t*)(P + 1048576);
  uint64_t* list_be = (uint64_t*)(P + 2097152);
  uint64_t* bmA = (uint64_t*)(P + 3145728);     // 4 MB each
  uint64_t* bmB = (uint64_t*)(P + 3145728 + 4194304);
  uint64_t* bmC = (uint64_t*)(P + 3145728 + 8388608);

  hipMemsetAsync(Z, 0, Zsize, stream);
  k_keys   <<<1, 128, 0, stream>>>(keys, kbg);
  k_hist256<<<BATCH * 16, 256, 0, stream>>>(x, gh256);
  k_otsu   <<<2, 64, 0, stream>>>(gh256, th);
  k_roi    <<<(BATCH * HW) / 256, 256, 0, stream>>>(x, th, bmA);
  k_rowmin <<<(BATCH * WPI) / 256, 256, 0, stream>>>(bmA, bmB);
  k_colmin <<<(BATCH * WPI) / 256, 256, 0, stream>>>(bmB, bmA);   // eroded ROI in A
  k_count  <<<BATCH, 256, 0, stream>>>(bmA, Efg);
  // fg select: top-1000 by score among eroded ROI  -> bmB
  k_sel_hist   <<<BATCH * 4, 1024, 0, stream>>>(bmA, keys, 0, Efg, gh_fg);
  k_sel_scan   <<<2, 64, 0, stream>>>(gh_fg, Efg, b1_fg, r1_fg);
  k_sel_collect<<<BATCH * 4, 1024, 0, stream>>>(bmA, keys, 0, b1_fg, cnt_fg, list_fg);
  k_cut        <<<2, 64, 0, stream>>>(b1_fg, r1_fg, cnt_fg, list_fg, cut_fg);
  k_sel_emit   <<<BATCH * 4, 1024, 0, stream>>>(bmA, keys, 0, cut_fg, bmB);
  // bg eligibility: bottom-K floats -> bmC
  k_bg_hist    <<<BATCH * 4, 1024, 0, stream>>>(x, gh_be);
  k_bg_scan    <<<2, 64, 0, stream>>>(gh_be, kbg, b1_be, r1_be);
  k_bg_collect <<<BATCH * 4, 1024, 0, stream>>>(x, b1_be, cnt_be, list_be);
  k_cut        <<<2, 64, 0, stream>>>(b1_be, r1_be, cnt_be, list_be, cut_be);
  k_bg_emit    <<<BATCH * 4, 1024, 0, stream>>>(x, cut_be, bmC);
  // bg select: top-1000 by score among eligible -> bmA  (E = kbg, always >1000)
  k_sel_hist   <<<BATCH * 4, 1024, 0, stream>>>(bmC, keys, 2, kbg, gh_bg);
  k_sel_scan   <<<2, 64, 0, stream>>>(gh_bg, kbg, b1_bg, r1_bg);
  k_sel_collect<<<BATCH * 4, 1024, 0, stream>>>(bmC, keys, 2, b1_bg, cnt_bg, list_bg);
  k_cut        <<<2, 64, 0, stream>>>(b1_bg, r1_bg, cnt_bg, list_bg, cut_bg);
  k_sel_emit   <<<BATCH * 4, 1024, 0, stream>>>(bmC, keys, 2, cut_bg, bmA);
  // dilation + compose
  k_rowdil <<<(BATCH * WPI) / 256, 256, 0, stream>>>(bmB, bmC);   // fg row-dil in C
  k_rowdil <<<(BATCH * WPI) / 256, 256, 0, stream>>>(bmA, bmB);   // bg row-dil in B
  k_compose<<<(BATCH * HW) / 256, 256, 0, stream>>>(bmC, bmB, out);
}

// Round 3
// 1388.286 us; speedup vs baseline: 1.7670x; 1.5674x over previous
//
#include <hip/hip_runtime.h>
#include <cstdint>

constexpr int BATCH = 128;
constexpr int H = 512, W = 512;
constexpr int HW = H * W;       // 2^18
constexpr int WPR = W / 64;     // 8 words per row
constexpr int WPI = HW / 64;    // 4096 words per image
constexpr int NSEED = 1000;
constexpr int CAP = 1024;       // per-image tie-bin list capacity (expected ~64)

// ---------------- Threefry-2x32 (20 rounds), bit-exact vs JAX ----------------
__device__ __forceinline__ uint32_t rotl32(uint32_t v, int d) {
  return (v << d) | (v >> (32 - d));
}

__device__ __forceinline__ void tf2x32(uint32_t k0, uint32_t k1,
                                       uint32_t x0, uint32_t x1,
                                       uint32_t &o0, uint32_t &o1) {
  uint32_t ks2 = k0 ^ k1 ^ 0x1BD11BDAu;
  x0 += k0; x1 += k1;
  x0 += x1; x1 = rotl32(x1, 13); x1 ^= x0;
  x0 += x1; x1 = rotl32(x1, 15); x1 ^= x0;
  x0 += x1; x1 = rotl32(x1, 26); x1 ^= x0;
  x0 += x1; x1 = rotl32(x1, 6);  x1 ^= x0;
  x0 += k1; x1 += ks2 + 1u;
  x0 += x1; x1 = rotl32(x1, 17); x1 ^= x0;
  x0 += x1; x1 = rotl32(x1, 29); x1 ^= x0;
  x0 += x1; x1 = rotl32(x1, 16); x1 ^= x0;
  x0 += x1; x1 = rotl32(x1, 24); x1 ^= x0;
  x0 += ks2; x1 += k0 + 2u;
  x0 += x1; x1 = rotl32(x1, 13); x1 ^= x0;
  x0 += x1; x1 = rotl32(x1, 15); x1 ^= x0;
  x0 += x1; x1 = rotl32(x1, 26); x1 ^= x0;
  x0 += x1; x1 = rotl32(x1, 6);  x1 ^= x0;
  x0 += k0; x1 += k1 + 3u;
  x0 += x1; x1 = rotl32(x1, 17); x1 ^= x0;
  x0 += x1; x1 = rotl32(x1, 29); x1 ^= x0;
  x0 += x1; x1 = rotl32(x1, 16); x1 ^= x0;
  x0 += x1; x1 = rotl32(x1, 24); x1 ^= x0;
  x0 += k1; x1 += ks2 + 4u;
  x0 += x1; x1 = rotl32(x1, 13); x1 ^= x0;
  x0 += x1; x1 = rotl32(x1, 15); x1 ^= x0;
  x0 += x1; x1 = rotl32(x1, 26); x1 ^= x0;
  x0 += x1; x1 = rotl32(x1, 6);  x1 ^= x0;
  x0 += ks2; x1 += k0 + 5u;
  o0 = x0; o1 = x1;
}

// random bits for pixel i of a size-HW uniform draw (partitionable threefry)
__device__ __forceinline__ uint32_t score_bits(uint32_t k0, uint32_t k1, uint32_t i) {
  uint32_t a, c; tf2x32(k0, k1, 0u, i, a, c);
  return a ^ c;
}

// ------------- exact replica of jax.lax.associative_scan cumsum tree ---------
__device__ void tree_cumsum256(float* L, float* S) {
  const int off[9] = {0, 256, 384, 448, 480, 496, 504, 508, 510};
  const int sz[9]  = {256, 128, 64, 32, 16, 8, 4, 2, 1};
  for (int l = 0; l < 8; ++l) {
    int o = off[l], on = off[l + 1], n = sz[l + 1];
    for (int i = 0; i < n; ++i)
      L[on + i] = __fadd_rn(L[o + 2 * i], L[o + 2 * i + 1]);
  }
  S[off[8]] = L[off[8]];
  for (int l = 7; l >= 0; --l) {
    int o = off[l], on = off[l + 1], n = sz[l], h = n / 2;
    S[o] = L[o];
    for (int k = 0; k < h; ++k) S[o + 2 * k + 1] = S[on + k];
    for (int k = 1; k < h; ++k) S[o + 2 * k] = __fadd_rn(S[on + k - 1], L[o + 2 * k]);
  }
}

// ---------------- per-image keys + nbr_bg ----------------
__global__ void k_keys(uint32_t* __restrict__ keys, uint32_t* __restrict__ kbg) {
  int b = threadIdx.x;
  if (b >= BATCH) return;
  uint32_t kb0, kb1; tf2x32(0u, 42u, 0u, (uint32_t)b, kb0, kb1);
  uint32_t kf0, kf1; tf2x32(kb0, kb1, 0u, 0u, kf0, kf1);
  uint32_t kB0, kB1; tf2x32(kb0, kb1, 0u, 1u, kB0, kB1);
  uint32_t kz0, kz1; tf2x32(kb0, kb1, 0u, 2u, kz0, kz1);
  uint32_t za, zc; tf2x32(kz0, kz1, 0u, 0u, za, zc);
  uint32_t zb = za ^ zc;
  keys[b * 4 + 0] = kf0; keys[b * 4 + 1] = kf1;
  keys[b * 4 + 2] = kB0; keys[b * 4 + 3] = kB1;
  float uu = __uint_as_float((zb >> 9) | 0x3f800000u) - 1.0f;
  float span = __fsub_rn(0.7f, 0.3f);
  float z = __fadd_rn(__fmul_rn(uu, span), 0.3f);
  z = fmaxf(0.3f, z);
  float nb = ceilf(__fmul_rn(z, (float)HW));
  kbg[b] = (uint32_t)nb;
}

// ---------------- grid-wide 256-bin histogram ----------------
__global__ void k_hist256(const float* __restrict__ x, uint32_t* __restrict__ gh) {
  __shared__ uint32_t h[256];
  int b = blockIdx.x >> 4, sub = blockIdx.x & 15;
  int tid = threadIdx.x;
  h[tid] = 0;
  __syncthreads();
  const float* xb = x + (size_t)b * HW + sub * (HW / 16);
  for (int i = tid; i < HW / 16; i += 256) {
    float v = xb[i];
    int f = (int)floorf(__fmul_rn(v, 255.0f));
    f = min(max(f, 0), 255);
    atomicAdd(&h[f], 1u);
  }
  __syncthreads();
  if (h[tid]) atomicAdd(&gh[b * 256 + tid], h[tid]);
}

// ---------------- Otsu from histogram (1 thread per image) ----------------
__global__ void k_otsu(const uint32_t* __restrict__ gh, int* __restrict__ th_out) {
  int b = blockIdx.x * blockDim.x + threadIdx.x;
  if (b >= BATCH) return;
  float Lt[511], St[511], wc[256];
  const uint32_t* hist = gh + (size_t)b * 256;
  for (int i = 0; i < 256; ++i) Lt[i] = (float)hist[i];
  tree_cumsum256(Lt, St);
  for (int i = 0; i < 256; ++i) wc[i] = St[i];
  for (int i = 0; i < 256; ++i) Lt[i] = __fmul_rn((float)hist[i], (float)i);
  tree_cumsum256(Lt, St);   // St = m
  float total = (float)HW;
  float mT = St[255];
  float best = -1.0f; int bi = 0;
  for (int t = 0; t < 256; ++t) {
    float w = wc[t];
    float denom = __fmul_rn(w, __fsub_rn(total, w));
    float s = 0.0f;
    if (denom > 0.0f) {
      float d  = __fsub_rn(__fmul_rn(mT, w), __fmul_rn(total, St[t]));
      float nu = __fmul_rn(d, d);
      float dd = __fmul_rn(__fmul_rn(denom, total), total);
      s = __fdiv_rn(nu, dd);
    }
    if (s > best) { best = s; bi = t; }
  }
  if (bi == 0) bi = 1;
  if (bi == 255) bi = 254;
  th_out[b] = bi;
}

// ---------------- ROI bitmap: bit = floor(x*255) > th --------------------
__global__ void k_roi(const float* __restrict__ x, const int* __restrict__ th,
                      uint64_t* __restrict__ roi) {
  int p = blockIdx.x * blockDim.x + threadIdx.x;
  int b = p >> 18;
  float v = x[p];
  int f = (int)floorf(__fmul_rn(v, 255.0f));
  bool pred = f > th[b];
  uint64_t bw = __ballot(pred);
  if ((threadIdx.x & 63) == 0) roi[p >> 6] = bw;
}

// ---------- erosion: 11-wide row min (OOB = 1), then 11-tall col min --------
__global__ void k_rowmin(const uint64_t* __restrict__ in, uint64_t* __restrict__ out) {
  int w = blockIdx.x * blockDim.x + threadIdx.x;
  int c = w & (WPR - 1);
  uint64_t cur = in[w];
  uint64_t left  = (c > 0)       ? in[w - 1] : ~0ull;
  uint64_t right = (c < WPR - 1) ? in[w + 1] : ~0ull;
  uint64_t res = cur;
#pragma unroll
  for (int s = 1; s <= 5; ++s) {
    res &= (cur >> s) | (right << (64 - s));
    res &= (cur << s) | (left >> (64 - s));
  }
  out[w] = res;
}

__global__ void k_colmin(const uint64_t* __restrict__ in, uint64_t* __restrict__ out) {
  int w = blockIdx.x * blockDim.x + threadIdx.x;
  int wi = w & (WPI - 1);
  int r = wi >> 3;
  uint64_t res = in[w];
#pragma unroll
  for (int d = 1; d <= 5; ++d) {
    if (r >= d)     res &= in[w - WPR * d];
    if (r + d < H)  res &= in[w + WPR * d];
  }
  out[w] = res;
}

// ---------------- per-image popcount of a bitmap ----------------
__global__ void k_count(const uint64_t* __restrict__ bm, uint32_t* __restrict__ E) {
  int b = blockIdx.x, tid = threadIdx.x;
  uint32_t loc = 0;
  for (int w = tid; w < WPI; w += blockDim.x) loc += (uint32_t)__popcll(bm[(size_t)b * WPI + w]);
  atomicAdd(&E[b], loc);
}

// ============ generic top-NSEED-by-random-score select (grid-wide) ============
// bins: v = score>>9 (23 bits); L1 bin = v>>11 (4096 bins, scanned descending)
__global__ __launch_bounds__(1024) void k_sel_hist(const uint64_t* __restrict__ elig,
                                                   const uint32_t* __restrict__ keys, int koff,
                                                   const uint32_t* __restrict__ E,
                                                   uint32_t* __restrict__ gh) {
  int b = blockIdx.x >> 2, sub = blockIdx.x & 3;
  if (E[b] <= (uint32_t)NSEED) return;
  __shared__ uint32_t h[4096];
  int tid = threadIdx.x;
  for (int i = tid; i < 4096; i += 1024) h[i] = 0;
  __syncthreads();
  uint32_t k0 = keys[b * 4 + koff], k1 = keys[b * 4 + koff + 1];
  const uint64_t* eb = elig + (size_t)b * WPI;
  int base = sub * (HW / 4);
  for (int i = tid; i < HW / 4; i += 1024) {
    int p = base + i;
    if ((eb[p >> 6] >> (p & 63)) & 1ull) {
      uint32_t v = score_bits(k0, k1, (uint32_t)p) >> 9;
      atomicAdd(&h[v >> 11], 1u);
    }
  }
  __syncthreads();
  for (int i = tid; i < 4096; i += 1024)
    if (h[i]) atomicAdd(&gh[(size_t)b * 4096 + i], h[i]);
}

__global__ void k_sel_scan(const uint32_t* __restrict__ gh, const uint32_t* __restrict__ E,
                           uint32_t* __restrict__ b1a, uint32_t* __restrict__ r1a) {
  int b = blockIdx.x * blockDim.x + threadIdx.x;
  if (b >= BATCH) return;
  if (E[b] <= (uint32_t)NSEED) { b1a[b] = 0xFFFFFFFFu; r1a[b] = 0; return; }
  const uint32_t* h = gh + (size_t)b * 4096;
  uint32_t acc = 0, b1 = 0, r1 = 1;
  for (int bin = 4095; bin >= 0; --bin) {
    uint32_t c = h[bin];
    if (acc + c >= (uint32_t)NSEED) { b1 = (uint32_t)bin; r1 = (uint32_t)NSEED - acc; break; }
    acc += c;
  }
  b1a[b] = b1; r1a[b] = r1;
}

__global__ __launch_bounds__(1024) void k_sel_collect(const uint64_t* __restrict__ elig,
                                                      const uint32_t* __restrict__ keys, int koff,
                                                      const uint32_t* __restrict__ b1a,
                                                      uint32_t* __restrict__ cnt,
                                                      uint64_t* __restrict__ list) {
  int b = blockIdx.x >> 2, sub = blockIdx.x & 3;
  uint32_t b1 = b1a[b];
  if (b1 == 0xFFFFFFFFu) return;
  uint32_t k0 = keys[b * 4 + koff], k1 = keys[b * 4 + koff + 1];
  const uint64_t* eb = elig + (size_t)b * WPI;
  int tid = threadIdx.x;
  int base = sub * (HW / 4);
  for (int i = tid; i < HW / 4; i += 1024) {
    int p = base + i;
    if ((eb[p >> 6] >> (p & 63)) & 1ull) {
      uint32_t v = score_bits(k0, k1, (uint32_t)p) >> 9;
      if ((v >> 11) == b1) {
        uint32_t pos = atomicAdd(&cnt[b], 1u);
        if (pos < (uint32_t)CAP)
          list[(size_t)b * CAP + pos] = (((uint64_t)((~v) & 0x7FFFFFu)) << 18) | (uint32_t)p;
      }
    }
  }
}

// parallel LDS rank-selection: one block per image, thread i ranks key i.
// keys are distinct (pixel idx in low bits) -> exactly one thread has rank r-1.
__global__ __launch_bounds__(1024) void k_cut(const uint32_t* __restrict__ b1a,
                                              const uint32_t* __restrict__ r1a,
                                              const uint32_t* __restrict__ cnt,
                                              const uint64_t* __restrict__ list,
                                              uint64_t* __restrict__ cut) {
  __shared__ uint64_t ks[CAP];
  int b = blockIdx.x, tid = threadIdx.x;
  if (b1a[b] == 0xFFFFFFFFu) { if (tid == 0) cut[b] = ~0ull; return; }
  int n = min((int)cnt[b], CAP);
  if (n == 0) { if (tid == 0) cut[b] = 0; return; }
  const uint64_t* lb = list + (size_t)b * CAP;
  if (tid < n) ks[tid] = lb[tid];
  __syncthreads();
  int r = (int)r1a[b]; if (r > n) r = n; if (r < 1) r = 1;
  if (tid < n) {
    uint64_t mykey = ks[tid];
    int rank = 0;
    for (int i = 0; i < n; ++i) rank += (ks[i] < mykey) ? 1 : 0;
    if (rank == r - 1) cut[b] = mykey;
  }
}

__global__ __launch_bounds__(1024) void k_sel_emit(const uint64_t* __restrict__ elig,
                                                   const uint32_t* __restrict__ keys, int koff,
                                                   const uint64_t* __restrict__ cut,
                                                   uint64_t* __restrict__ out) {
  int b = blockIdx.x >> 2, sub = blockIdx.x & 3;
  uint32_t k0 = keys[b * 4 + koff], k1 = keys[b * 4 + koff + 1];
  uint64_t cutkey = cut[b];
  const uint64_t* eb = elig + (size_t)b * WPI;
  int tid = threadIdx.x;
  int wave = tid >> 6, lane = tid & 63;
  for (int wl = wave; wl < WPI / 4; wl += 16) {
    int w = sub * (WPI / 4) + wl;
    uint64_t ew = eb[w];
    int p = (w << 6) | lane;
    bool sel = false;
    if ((ew >> lane) & 1ull) {
      uint32_t v = score_bits(k0, k1, (uint32_t)p) >> 9;
      uint64_t key = (((uint64_t)((~v) & 0x7FFFFFu)) << 18) | (uint32_t)p;
      sel = key <= cutkey;
    }
    uint64_t bw = __ballot(sel);
    if (lane == 0) out[(size_t)b * WPI + w] = bw;
  }
}

// ============ bg eligibility: bottom-K by (float asc, idx asc), grid-wide =====
__global__ __launch_bounds__(1024) void k_bg_hist(const float* __restrict__ x,
                                                  uint32_t* __restrict__ gh) {
  int b = blockIdx.x >> 2, sub = blockIdx.x & 3;
  __shared__ uint32_t h[4096];
  int tid = threadIdx.x;
  for (int i = tid; i < 4096; i += 1024) h[i] = 0;
  __syncthreads();
  const float* xb = x + (size_t)b * HW + sub * (HW / 4);
  for (int i = tid; i < HW / 4; i += 1024) {
    int bin = (int)floorf(__fmul_rn(xb[i], 4096.0f));
    bin = min(max(bin, 0), 4095);
    atomicAdd(&h[bin], 1u);
  }
  __syncthreads();
  for (int i = tid; i < 4096; i += 1024)
    if (h[i]) atomicAdd(&gh[(size_t)b * 4096 + i], h[i]);
}

__global__ void k_bg_scan(const uint32_t* __restrict__ gh, const uint32_t* __restrict__ kbg,
                          uint32_t* __restrict__ b1a, uint32_t* __restrict__ r1a) {
  int b = blockIdx.x * blockDim.x + threadIdx.x;
  if (b >= BATCH) return;
  uint32_t K = kbg[b];
  const uint32_t* h = gh + (size_t)b * 4096;
  uint32_t acc = 0, b1 = 0, r1 = 1;
  for (int bin = 0; bin < 4096; ++bin) {
    uint32_t c = h[bin];
    if (acc + c >= K) { b1 = (uint32_t)bin; r1 = K - acc; break; }
    acc += c;
  }
  b1a[b] = b1; r1a[b] = r1;
}

__global__ __launch_bounds__(1024) void k_bg_collect(const float* __restrict__ x,
                                                     const uint32_t* __restrict__ b1a,
                                                     uint32_t* __restrict__ cnt,
                                                     uint64_t* __restrict__ list) {
  int b = blockIdx.x >> 2, sub = blockIdx.x & 3;
  uint32_t b1 = b1a[b];
  const float* xb = x + (size_t)b * HW;
  int tid = threadIdx.x;
  int base = sub * (HW / 4);
  for (int i = tid; i < HW / 4; i += 1024) {
    int p = base + i;
    float v = xb[p];
    int bin = (int)floorf(__fmul_rn(v, 4096.0f));
    bin = min(max(bin, 0), 4095);
    if ((uint32_t)bin == b1) {
      uint32_t pos = atomicAdd(&cnt[b], 1u);
      if (pos < (uint32_t)CAP)
        list[(size_t)b * CAP + pos] = (((uint64_t)__float_as_uint(v)) << 18) | (uint32_t)p;
    }
  }
}

__global__ __launch_bounds__(1024) void k_bg_emit(const float* __restrict__ x,
                                                  const uint64_t* __restrict__ cut,
                                                  uint64_t* __restrict__ out) {
  int b = blockIdx.x >> 2, sub = blockIdx.x & 3;
  uint64_t cutkey = cut[b];
  const float* xb = x + (size_t)b * HW;
  int tid = threadIdx.x;
  int wave = tid >> 6, lane = tid & 63;
  for (int wl = wave; wl < WPI / 4; wl += 16) {
    int w = sub * (WPI / 4) + wl;
    int p = (w << 6) | lane;
    uint64_t key = (((uint64_t)__float_as_uint(xb[p])) << 18) | (uint32_t)p;
    bool sel = key <= cutkey;
    uint64_t bw = __ballot(sel);
    if (lane == 0) out[(size_t)b * WPI + w] = bw;
  }
}

// -------- 3-wide row dilation (OR, OOB = 0) --------
__global__ void k_rowdil(const uint64_t* __restrict__ in, uint64_t* __restrict__ out) {
  int w = blockIdx.x * blockDim.x + threadIdx.x;
  int c = w & (WPR - 1);
  uint64_t cur = in[w];
  uint64_t left  = (c > 0)       ? in[w - 1] : 0ull;
  uint64_t right = (c < WPR - 1) ? in[w + 1] : 0ull;
  out[w] = cur | (cur << 1) | (left >> 63) | (cur >> 1) | (right << 63);
}

// -------- column dilation + overlap removal + compose --------
__global__ void k_compose(const uint64_t* __restrict__ fgrow, const uint64_t* __restrict__ bgrow,
                          int* __restrict__ out) {
  int p = blockIdx.x * blockDim.x + threadIdx.x;
  int q = p & (HW - 1);
  int r = q >> 9;
  int gw = p >> 6;
  uint64_t F = fgrow[gw], Bb = bgrow[gw];
  if (r > 0)     { F |= fgrow[gw - WPR]; Bb |= bgrow[gw - WPR]; }
  if (r < H - 1) { F |= fgrow[gw + WPR]; Bb |= bgrow[gw + WPR]; }
  uint64_t ov = F & Bb;
  F &= ~ov; Bb &= ~ov;
  int lane = p & 63;
  int val = ((F >> lane) & 1ull) ? 1 : (((Bb >> lane) & 1ull) ? 0 : -255);
  out[p] = val;
}

extern "C" void kernel_launch(void* const* d_in, const int* in_sizes, int n_in,
                              void* d_out, int out_size, void* d_ws, size_t ws_size,
                              hipStream_t stream) {
  (void)in_sizes; (void)n_in; (void)out_size; (void)ws_size;
  const float* x = (const float*)d_in[0];
  int* out = (int*)d_out;
  char* ws = (char*)d_ws;

  // ---- workspace layout (bytes) ----
  uint32_t* keys  = (uint32_t*)(ws + 0);        // 128*4 u32
  uint32_t* kbg   = (uint32_t*)(ws + 2048);     // 128
  int*      th    = (int*)     (ws + 2560);     // 128
  uint32_t* b1_fg = (uint32_t*)(ws + 3072);
  uint32_t* r1_fg = (uint32_t*)(ws + 3584);
  uint32_t* b1_bg = (uint32_t*)(ws + 4096);
  uint32_t* r1_bg = (uint32_t*)(ws + 4608);
  uint32_t* b1_be = (uint32_t*)(ws + 5120);
  uint32_t* r1_be = (uint32_t*)(ws + 5632);
  uint64_t* cut_fg = (uint64_t*)(ws + 6144);    // 128 u64
  uint64_t* cut_bg = (uint64_t*)(ws + 7168);
  uint64_t* cut_be = (uint64_t*)(ws + 8192);
  // zeroed region [16384, 16384+6424576)
  char* Z = ws + 16384;
  uint32_t* Efg    = (uint32_t*)(Z + 0);        // 512 B
  uint32_t* cnt_fg = (uint32_t*)(Z + 512);
  uint32_t* cnt_bg = (uint32_t*)(Z + 1024);
  uint32_t* cnt_be = (uint32_t*)(Z + 1536);
  uint32_t* gh256  = (uint32_t*)(Z + 2048);     // 128*256*4 = 131072
  uint32_t* gh_fg  = (uint32_t*)(Z + 133120);   // 128*4096*4 = 2 MB
  uint32_t* gh_bg  = (uint32_t*)(Z + 2230272);
  uint32_t* gh_be  = (uint32_t*)(Z + 4327424);
  size_t Zsize = 4327424 + 2097152;             // = 6424576
  char* P = Z + Zsize;
  uint64_t* list_fg = (uint64_t*)(P + 0);       // 128*CAP*8 = 1 MB
  uint64_t* list_bg = (uint64_t*)(P + 1048576);
  uint64_t* list_be = (uint64_t*)(P + 2097152);
  uint64_t* bmA = (uint64_t*)(P + 3145728);     // 4 MB each
  uint64_t* bmB = (uint64_t*)(P + 3145728 + 4194304);
  uint64_t* bmC = (uint64_t*)(P + 3145728 + 8388608);

  hipMemsetAsync(Z, 0, Zsize, stream);
  k_keys   <<<1, 128, 0, stream>>>(keys, kbg);
  k_hist256<<<BATCH * 16, 256, 0, stream>>>(x, gh256);
  k_otsu   <<<2, 64, 0, stream>>>(gh256, th);
  k_roi    <<<(BATCH * HW) / 256, 256, 0, stream>>>(x, th, bmA);
  k_rowmin <<<(BATCH * WPI) / 256, 256, 0, stream>>>(bmA, bmB);
  k_colmin <<<(BATCH * WPI) / 256, 256, 0, stream>>>(bmB, bmA);   // eroded ROI in A
  k_count  <<<BATCH, 256, 0, stream>>>(bmA, Efg);
  // fg select: top-1000 by score among eroded ROI  -> bmB
  k_sel_hist   <<<BATCH * 4, 1024, 0, stream>>>(bmA, keys, 0, Efg, gh_fg);
  k_sel_scan   <<<2, 64, 0, stream>>>(gh_fg, Efg, b1_fg, r1_fg);
  k_sel_collect<<<BATCH * 4, 1024, 0, stream>>>(bmA, keys, 0, b1_fg, cnt_fg, list_fg);
  k_cut        <<<BATCH, 1024, 0, stream>>>(b1_fg, r1_fg, cnt_fg, list_fg, cut_fg);
  k_sel_emit   <<<BATCH * 4, 1024, 0, stream>>>(bmA, keys, 0, cut_fg, bmB);
  // bg eligibility: bottom-K floats -> bmC
  k_bg_hist    <<<BATCH * 4, 1024, 0, stream>>>(x, gh_be);
  k_bg_scan    <<<2, 64, 0, stream>>>(gh_be, kbg, b1_be, r1_be);
  k_bg_collect <<<BATCH * 4, 1024, 0, stream>>>(x, b1_be, cnt_be, list_be);
  k_cut        <<<BATCH, 1024, 0, stream>>>(b1_be, r1_be, cnt_be, list_be, cut_be);
  k_bg_emit    <<<BATCH * 4, 1024, 0, stream>>>(x, cut_be, bmC);
  // bg select: top-1000 by score among eligible -> bmA  (E = kbg, always >1000)
  k_sel_hist   <<<BATCH * 4, 1024, 0, stream>>>(bmC, keys, 2, kbg, gh_bg);
  k_sel_scan   <<<2, 64, 0, stream>>>(gh_bg, kbg, b1_bg, r1_bg);
  k_sel_collect<<<BATCH * 4, 1024, 0, stream>>>(bmC, keys, 2, b1_bg, cnt_bg, list_bg);
  k_cut        <<<BATCH, 1024, 0, stream>>>(b1_bg, r1_bg, cnt_bg, list_bg, cut_bg);
  k_sel_emit   <<<BATCH * 4, 1024, 0, stream>>>(bmC, keys, 2, cut_bg, bmA);
  // dilation + compose
  k_rowdil <<<(BATCH * WPI) / 256, 256, 0, stream>>>(bmB, bmC);   // fg row-dil in C
  k_rowdil <<<(BATCH * WPI) / 256, 256, 0, stream>>>(bmA, bmB);   // bg row-dil in B
  k_compose<<<(BATCH * HW) / 256, 256, 0, stream>>>(bmC, bmB, out);
}

// Round 4
// 833.425 us; speedup vs baseline: 2.9433x; 1.6658x over previous
//
#include <hip/hip_runtime.h>
#include <cstdint>

constexpr int BATCH = 128;
constexpr int H = 512, W = 512;
constexpr int HW = H * W;       // 2^18
constexpr int WPR = W / 64;     // 8 words per row
constexpr int WPI = HW / 64;    // 4096 words per image
constexpr int NSEED = 1000;
constexpr int CAP = 1024;       // per-image tie-bin list capacity (expected ~64)

// ---------------- Threefry-2x32 (20 rounds), bit-exact vs JAX ----------------
__device__ __forceinline__ uint32_t rotl32(uint32_t v, int d) {
  return (v << d) | (v >> (32 - d));
}

__device__ __forceinline__ void tf2x32(uint32_t k0, uint32_t k1,
                                       uint32_t x0, uint32_t x1,
                                       uint32_t &o0, uint32_t &o1) {
  uint32_t ks2 = k0 ^ k1 ^ 0x1BD11BDAu;
  x0 += k0; x1 += k1;
  x0 += x1; x1 = rotl32(x1, 13); x1 ^= x0;
  x0 += x1; x1 = rotl32(x1, 15); x1 ^= x0;
  x0 += x1; x1 = rotl32(x1, 26); x1 ^= x0;
  x0 += x1; x1 = rotl32(x1, 6);  x1 ^= x0;
  x0 += k1; x1 += ks2 + 1u;
  x0 += x1; x1 = rotl32(x1, 17); x1 ^= x0;
  x0 += x1; x1 = rotl32(x1, 29); x1 ^= x0;
  x0 += x1; x1 = rotl32(x1, 16); x1 ^= x0;
  x0 += x1; x1 = rotl32(x1, 24); x1 ^= x0;
  x0 += ks2; x1 += k0 + 2u;
  x0 += x1; x1 = rotl32(x1, 13); x1 ^= x0;
  x0 += x1; x1 = rotl32(x1, 15); x1 ^= x0;
  x0 += x1; x1 = rotl32(x1, 26); x1 ^= x0;
  x0 += x1; x1 = rotl32(x1, 6);  x1 ^= x0;
  x0 += k0; x1 += k1 + 3u;
  x0 += x1; x1 = rotl32(x1, 17); x1 ^= x0;
  x0 += x1; x1 = rotl32(x1, 29); x1 ^= x0;
  x0 += x1; x1 = rotl32(x1, 16); x1 ^= x0;
  x0 += x1; x1 = rotl32(x1, 24); x1 ^= x0;
  x0 += k1; x1 += ks2 + 4u;
  x0 += x1; x1 = rotl32(x1, 13); x1 ^= x0;
  x0 += x1; x1 = rotl32(x1, 15); x1 ^= x0;
  x0 += x1; x1 = rotl32(x1, 26); x1 ^= x0;
  x0 += x1; x1 = rotl32(x1, 6);  x1 ^= x0;
  x0 += ks2; x1 += k0 + 5u;
  o0 = x0; o1 = x1;
}

// random bits for pixel i of a size-HW uniform draw (partitionable threefry)
__device__ __forceinline__ uint32_t score_bits(uint32_t k0, uint32_t k1, uint32_t i) {
  uint32_t a, c; tf2x32(k0, k1, 0u, i, a, c);
  return a ^ c;
}

// ---------------- per-image keys + nbr_bg ----------------
__global__ void k_keys(uint32_t* __restrict__ keys, uint32_t* __restrict__ kbg) {
  int b = threadIdx.x;
  if (b >= BATCH) return;
  uint32_t kb0, kb1; tf2x32(0u, 42u, 0u, (uint32_t)b, kb0, kb1);
  uint32_t kf0, kf1; tf2x32(kb0, kb1, 0u, 0u, kf0, kf1);
  uint32_t kB0, kB1; tf2x32(kb0, kb1, 0u, 1u, kB0, kB1);
  uint32_t kz0, kz1; tf2x32(kb0, kb1, 0u, 2u, kz0, kz1);
  uint32_t za, zc; tf2x32(kz0, kz1, 0u, 0u, za, zc);
  uint32_t zb = za ^ zc;
  keys[b * 4 + 0] = kf0; keys[b * 4 + 1] = kf1;
  keys[b * 4 + 2] = kB0; keys[b * 4 + 3] = kB1;
  float uu = __uint_as_float((zb >> 9) | 0x3f800000u) - 1.0f;
  float span = __fsub_rn(0.7f, 0.3f);
  float z = __fadd_rn(__fmul_rn(uu, span), 0.3f);
  z = fmaxf(0.3f, z);
  float nb = ceilf(__fmul_rn(z, (float)HW));
  kbg[b] = (uint32_t)nb;
}

// ---------------- grid-wide 256-bin histogram ----------------
__global__ void k_hist256(const float* __restrict__ x, uint32_t* __restrict__ gh) {
  __shared__ uint32_t h[256];
  int b = blockIdx.x >> 4, sub = blockIdx.x & 15;
  int tid = threadIdx.x;
  h[tid] = 0;
  __syncthreads();
  const float* xb = x + (size_t)b * HW + sub * (HW / 16);
  for (int i = tid; i < HW / 16; i += 256) {
    float v = xb[i];
    int f = (int)floorf(__fmul_rn(v, 255.0f));
    f = min(max(f, 0), 255);
    atomicAdd(&h[f], 1u);
  }
  __syncthreads();
  if (h[tid]) atomicAdd(&gh[b * 256 + tid], h[tid]);
}

// ------- block-parallel Otsu: exact associative_scan tree in LDS -------
// tree levels: off = {0,256,384,448,480,496,504,508,510}
__device__ __forceinline__ void lds_tree_cumsum256(float* L, float* S, int tid) {
  const int off[9] = {0, 256, 384, 448, 480, 496, 504, 508, 510};
  const int sz[9]  = {256, 128, 64, 32, 16, 8, 4, 2, 1};
  // up-sweep: pairwise adds, level-parallel (exact tree order)
  for (int l = 0; l < 8; ++l) {
    int o = off[l], on = off[l + 1], n = sz[l + 1];
    if (tid < n) L[on + tid] = __fadd_rn(L[o + 2 * tid], L[o + 2 * tid + 1]);
    __syncthreads();
  }
  if (tid == 0) S[off[8]] = L[off[8]];
  __syncthreads();
  // down-sweep
  for (int l = 7; l >= 0; --l) {
    int o = off[l], on = off[l + 1], hn = sz[l] / 2;
    if (tid == 0) S[o] = L[o];
    if (tid < hn) S[o + 2 * tid + 1] = S[on + tid];
    if (tid >= 1 && tid < hn) S[o + 2 * tid] = __fadd_rn(S[on + tid - 1], L[o + 2 * tid]);
    __syncthreads();
  }
}

__global__ __launch_bounds__(256) void k_otsu(const uint32_t* __restrict__ gh,
                                              int* __restrict__ th_out) {
  __shared__ float L[511], S[511], wc[256], mm[256];
  __shared__ float sv[256];
  __shared__ int si[256];
  int b = blockIdx.x, tid = threadIdx.x;
  const uint32_t* hist = gh + (size_t)b * 256;
  uint32_t hv = hist[tid];
  L[tid] = (float)hv;
  __syncthreads();
  lds_tree_cumsum256(L, S, tid);
  wc[tid] = S[tid];
  __syncthreads();
  L[tid] = __fmul_rn((float)hv, (float)tid);
  __syncthreads();
  lds_tree_cumsum256(L, S, tid);
  mm[tid] = S[tid];
  __syncthreads();
  float total = (float)HW;
  float mT = mm[255];
  {
    float w = wc[tid];
    float denom = __fmul_rn(w, __fsub_rn(total, w));
    float s = 0.0f;
    if (denom > 0.0f) {
      float d  = __fsub_rn(__fmul_rn(mT, w), __fmul_rn(total, mm[tid]));
      float nu = __fmul_rn(d, d);
      float dd = __fmul_rn(__fmul_rn(denom, total), total);
      s = __fdiv_rn(nu, dd);
    }
    sv[tid] = s; si[tid] = tid;
  }
  __syncthreads();
  // argmax, first occurrence: larger s wins; tie -> smaller index
  for (int st = 128; st >= 1; st >>= 1) {
    if (tid < st) {
      float s2 = sv[tid + st]; int i2 = si[tid + st];
      if (s2 > sv[tid] || (s2 == sv[tid] && i2 < si[tid])) { sv[tid] = s2; si[tid] = i2; }
    }
    __syncthreads();
  }
  if (tid == 0) {
    int bi = si[0];
    if (bi == 0) bi = 1;
    if (bi == 255) bi = 254;
    th_out[b] = bi;
  }
}

// ---------------- ROI bitmap: bit = floor(x*255) > th --------------------
__global__ void k_roi(const float* __restrict__ x, const int* __restrict__ th,
                      uint64_t* __restrict__ roi) {
  int p = blockIdx.x * blockDim.x + threadIdx.x;
  int b = p >> 18;
  float v = x[p];
  int f = (int)floorf(__fmul_rn(v, 255.0f));
  bool pred = f > th[b];
  uint64_t bw = __ballot(pred);
  if ((threadIdx.x & 63) == 0) roi[p >> 6] = bw;
}

// ---------- erosion: 11-wide row min (OOB = 1), then 11-tall col min --------
__global__ void k_rowmin(const uint64_t* __restrict__ in, uint64_t* __restrict__ out) {
  int w = blockIdx.x * blockDim.x + threadIdx.x;
  int c = w & (WPR - 1);
  uint64_t cur = in[w];
  uint64_t left  = (c > 0)       ? in[w - 1] : ~0ull;
  uint64_t right = (c < WPR - 1) ? in[w + 1] : ~0ull;
  uint64_t res = cur;
#pragma unroll
  for (int s = 1; s <= 5; ++s) {
    res &= (cur >> s) | (right << (64 - s));
    res &= (cur << s) | (left >> (64 - s));
  }
  out[w] = res;
}

__global__ void k_colmin(const uint64_t* __restrict__ in, uint64_t* __restrict__ out) {
  int w = blockIdx.x * blockDim.x + threadIdx.x;
  int wi = w & (WPI - 1);
  int r = wi >> 3;
  uint64_t res = in[w];
#pragma unroll
  for (int d = 1; d <= 5; ++d) {
    if (r >= d)     res &= in[w - WPR * d];
    if (r + d < H)  res &= in[w + WPR * d];
  }
  out[w] = res;
}

// ---------------- per-image popcount of a bitmap ----------------
__global__ void k_count(const uint64_t* __restrict__ bm, uint32_t* __restrict__ E) {
  int b = blockIdx.x, tid = threadIdx.x;
  uint32_t loc = 0;
  for (int w = tid; w < WPI; w += blockDim.x) loc += (uint32_t)__popcll(bm[(size_t)b * WPI + w]);
  atomicAdd(&E[b], loc);
}

// ============ generic top-NSEED-by-random-score select (grid-wide) ============
// bins: v = score>>9 (23 bits); L1 bin = v>>11 (4096 bins, scanned descending)
__global__ __launch_bounds__(1024) void k_sel_hist(const uint64_t* __restrict__ elig,
                                                   const uint32_t* __restrict__ keys, int koff,
                                                   const uint32_t* __restrict__ E,
                                                   uint32_t* __restrict__ gh) {
  int b = blockIdx.x >> 2, sub = blockIdx.x & 3;
  if (E[b] <= (uint32_t)NSEED) return;
  __shared__ uint32_t h[4096];
  int tid = threadIdx.x;
  for (int i = tid; i < 4096; i += 1024) h[i] = 0;
  __syncthreads();
  uint32_t k0 = keys[b * 4 + koff], k1 = keys[b * 4 + koff + 1];
  const uint64_t* eb = elig + (size_t)b * WPI;
  int base = sub * (HW / 4);
  for (int i = tid; i < HW / 4; i += 1024) {
    int p = base + i;
    if ((eb[p >> 6] >> (p & 63)) & 1ull) {
      uint32_t v = score_bits(k0, k1, (uint32_t)p) >> 9;
      atomicAdd(&h[v >> 11], 1u);
    }
  }
  __syncthreads();
  for (int i = tid; i < 4096; i += 1024)
    if (h[i]) atomicAdd(&gh[(size_t)b * 4096 + i], h[i]);
}

// parallel scan (descending): LDS-staged histogram, chunk partials, tiny serial tail
__global__ __launch_bounds__(256) void k_scan_desc(const uint32_t* __restrict__ gh,
                                                   const uint32_t* __restrict__ E,
                                                   uint32_t* __restrict__ b1a,
                                                   uint32_t* __restrict__ r1a) {
  __shared__ uint32_t h[4096];
  __shared__ uint32_t ps[256];
  int b = blockIdx.x, tid = threadIdx.x;
  if (E[b] <= (uint32_t)NSEED) { if (tid == 0) { b1a[b] = 0xFFFFFFFFu; r1a[b] = 0; } return; }
  const uint32_t* g = gh + (size_t)b * 4096;
  for (int i = tid; i < 4096; i += 256) h[i] = g[i];
  __syncthreads();
  uint32_t s = 0;
#pragma unroll
  for (int i = 0; i < 16; ++i) s += h[tid * 16 + i];
  ps[tid] = s;
  __syncthreads();
  if (tid == 0) {
    uint32_t acc = 0, b1 = 0, r1 = 1;
    for (int c = 255; c >= 0; --c) {
      if (acc + ps[c] >= (uint32_t)NSEED) {
        for (int bin = c * 16 + 15; bin >= c * 16; --bin) {
          uint32_t cc = h[bin];
          if (acc + cc >= (uint32_t)NSEED) { b1 = (uint32_t)bin; r1 = (uint32_t)NSEED - acc; break; }
          acc += cc;
        }
        break;
      }
      acc += ps[c];
    }
    b1a[b] = b1; r1a[b] = r1;
  }
}

// parallel scan (ascending), K per image
__global__ __launch_bounds__(256) void k_scan_asc(const uint32_t* __restrict__ gh,
                                                  const uint32_t* __restrict__ Ka,
                                                  uint32_t* __restrict__ b1a,
                                                  uint32_t* __restrict__ r1a) {
  __shared__ uint32_t h[4096];
  __shared__ uint32_t ps[256];
  int b = blockIdx.x, tid = threadIdx.x;
  uint32_t K = Ka[b];
  const uint32_t* g = gh + (size_t)b * 4096;
  for (int i = tid; i < 4096; i += 256) h[i] = g[i];
  __syncthreads();
  uint32_t s = 0;
#pragma unroll
  for (int i = 0; i < 16; ++i) s += h[tid * 16 + i];
  ps[tid] = s;
  __syncthreads();
  if (tid == 0) {
    uint32_t acc = 0, b1 = 0, r1 = 1;
    for (int c = 0; c < 256; ++c) {
      if (acc + ps[c] >= K) {
        for (int bin = c * 16; bin < c * 16 + 16; ++bin) {
          uint32_t cc = h[bin];
          if (acc + cc >= K) { b1 = (uint32_t)bin; r1 = K - acc; break; }
          acc += cc;
        }
        break;
      }
      acc += ps[c];
    }
    b1a[b] = b1; r1a[b] = r1;
  }
}

__global__ __launch_bounds__(1024) void k_sel_collect(const uint64_t* __restrict__ elig,
                                                      const uint32_t* __restrict__ keys, int koff,
                                                      const uint32_t* __restrict__ b1a,
                                                      uint32_t* __restrict__ cnt,
                                                      uint64_t* __restrict__ list) {
  int b = blockIdx.x >> 2, sub = blockIdx.x & 3;
  uint32_t b1 = b1a[b];
  if (b1 == 0xFFFFFFFFu) return;
  uint32_t k0 = keys[b * 4 + koff], k1 = keys[b * 4 + koff + 1];
  const uint64_t* eb = elig + (size_t)b * WPI;
  int tid = threadIdx.x;
  int base = sub * (HW / 4);
  for (int i = tid; i < HW / 4; i += 1024) {
    int p = base + i;
    if ((eb[p >> 6] >> (p & 63)) & 1ull) {
      uint32_t v = score_bits(k0, k1, (uint32_t)p) >> 9;
      if ((v >> 11) == b1) {
        uint32_t pos = atomicAdd(&cnt[b], 1u);
        if (pos < (uint32_t)CAP)
          list[(size_t)b * CAP + pos] = (((uint64_t)((~v) & 0x7FFFFFu)) << 18) | (uint32_t)p;
      }
    }
  }
}

// parallel LDS rank-selection: one block per image, thread i ranks key i.
// keys are distinct (pixel idx in low bits) -> exactly one thread has rank r-1.
__global__ __launch_bounds__(1024) void k_cut(const uint32_t* __restrict__ b1a,
                                              const uint32_t* __restrict__ r1a,
                                              const uint32_t* __restrict__ cnt,
                                              const uint64_t* __restrict__ list,
                                              uint64_t* __restrict__ cut) {
  __shared__ uint64_t ks[CAP];
  int b = blockIdx.x, tid = threadIdx.x;
  if (b1a[b] == 0xFFFFFFFFu) { if (tid == 0) cut[b] = ~0ull; return; }
  int n = min((int)cnt[b], CAP);
  if (n == 0) { if (tid == 0) cut[b] = 0; return; }
  const uint64_t* lb = list + (size_t)b * CAP;
  if (tid < n) ks[tid] = lb[tid];
  __syncthreads();
  int r = (int)r1a[b]; if (r > n) r = n; if (r < 1) r = 1;
  if (tid < n) {
    uint64_t mykey = ks[tid];
    int rank = 0;
    for (int i = 0; i < n; ++i) rank += (ks[i] < mykey) ? 1 : 0;
    if (rank == r - 1) cut[b] = mykey;
  }
}

__global__ __launch_bounds__(1024) void k_sel_emit(const uint64_t* __restrict__ elig,
                                                   const uint32_t* __restrict__ keys, int koff,
                                                   const uint64_t* __restrict__ cut,
                                                   uint64_t* __restrict__ out) {
  int b = blockIdx.x >> 2, sub = blockIdx.x & 3;
  uint32_t k0 = keys[b * 4 + koff], k1 = keys[b * 4 + koff + 1];
  uint64_t cutkey = cut[b];
  const uint64_t* eb = elig + (size_t)b * WPI;
  int tid = threadIdx.x;
  int wave = tid >> 6, lane = tid & 63;
  for (int wl = wave; wl < WPI / 4; wl += 16) {
    int w = sub * (WPI / 4) + wl;
    uint64_t ew = eb[w];
    int p = (w << 6) | lane;
    bool sel = false;
    if ((ew >> lane) & 1ull) {
      uint32_t v = score_bits(k0, k1, (uint32_t)p) >> 9;
      uint64_t key = (((uint64_t)((~v) & 0x7FFFFFu)) << 18) | (uint32_t)p;
      sel = key <= cutkey;
    }
    uint64_t bw = __ballot(sel);
    if (lane == 0) out[(size_t)b * WPI + w] = bw;
  }
}

// ============ bg eligibility: bottom-K by (float asc, idx asc), grid-wide =====
__global__ __launch_bounds__(1024) void k_bg_hist(const float* __restrict__ x,
                                                  uint32_t* __restrict__ gh) {
  int b = blockIdx.x >> 2, sub = blockIdx.x & 3;
  __shared__ uint32_t h[4096];
  int tid = threadIdx.x;
  for (int i = tid; i < 4096; i += 1024) h[i] = 0;
  __syncthreads();
  const float* xb = x + (size_t)b * HW + sub * (HW / 4);
  for (int i = tid; i < HW / 4; i += 1024) {
    int bin = (int)floorf(__fmul_rn(xb[i], 4096.0f));
    bin = min(max(bin, 0), 4095);
    atomicAdd(&h[bin], 1u);
  }
  __syncthreads();
  for (int i = tid; i < 4096; i += 1024)
    if (h[i]) atomicAdd(&gh[(size_t)b * 4096 + i], h[i]);
}

__global__ __launch_bounds__(1024) void k_bg_collect(const float* __restrict__ x,
                                                     const uint32_t* __restrict__ b1a,
                                                     uint32_t* __restrict__ cnt,
                                                     uint64_t* __restrict__ list) {
  int b = blockIdx.x >> 2, sub = blockIdx.x & 3;
  uint32_t b1 = b1a[b];
  const float* xb = x + (size_t)b * HW;
  int tid = threadIdx.x;
  int base = sub * (HW / 4);
  for (int i = tid; i < HW / 4; i += 1024) {
    int p = base + i;
    float v = xb[p];
    int bin = (int)floorf(__fmul_rn(v, 4096.0f));
    bin = min(max(bin, 0), 4095);
    if ((uint32_t)bin == b1) {
      uint32_t pos = atomicAdd(&cnt[b], 1u);
      if (pos < (uint32_t)CAP)
        list[(size_t)b * CAP + pos] = (((uint64_t)__float_as_uint(v)) << 18) | (uint32_t)p;
    }
  }
}

__global__ __launch_bounds__(1024) void k_bg_emit(const float* __restrict__ x,
                                                  const uint64_t* __restrict__ cut,
                                                  uint64_t* __restrict__ out) {
  int b = blockIdx.x >> 2, sub = blockIdx.x & 3;
  uint64_t cutkey = cut[b];
  const float* xb = x + (size_t)b * HW;
  int tid = threadIdx.x;
  int wave = tid >> 6, lane = tid & 63;
  for (int wl = wave; wl < WPI / 4; wl += 16) {
    int w = sub * (WPI / 4) + wl;
    int p = (w << 6) | lane;
    uint64_t key = (((uint64_t)__float_as_uint(xb[p])) << 18) | (uint32_t)p;
    bool sel = key <= cutkey;
    uint64_t bw = __ballot(sel);
    if (lane == 0) out[(size_t)b * WPI + w] = bw;
  }
}

// -------- 3-wide row dilation (OR, OOB = 0) --------
__global__ void k_rowdil(const uint64_t* __restrict__ in, uint64_t* __restrict__ out) {
  int w = blockIdx.x * blockDim.x + threadIdx.x;
  int c = w & (WPR - 1);
  uint64_t cur = in[w];
  uint64_t left  = (c > 0)       ? in[w - 1] : 0ull;
  uint64_t right = (c < WPR - 1) ? in[w + 1] : 0ull;
  out[w] = cur | (cur << 1) | (left >> 63) | (cur >> 1) | (right << 63);
}

// -------- column dilation + overlap removal + compose --------
__global__ void k_compose(const uint64_t* __restrict__ fgrow, const uint64_t* __restrict__ bgrow,
                          int* __restrict__ out) {
  int p = blockIdx.x * blockDim.x + threadIdx.x;
  int q = p & (HW - 1);
  int r = q >> 9;
  int gw = p >> 6;
  uint64_t F = fgrow[gw], Bb = bgrow[gw];
  if (r > 0)     { F |= fgrow[gw - WPR]; Bb |= bgrow[gw - WPR]; }
  if (r < H - 1) { F |= fgrow[gw + WPR]; Bb |= bgrow[gw + WPR]; }
  uint64_t ov = F & Bb;
  F &= ~ov; Bb &= ~ov;
  int lane = p & 63;
  int val = ((F >> lane) & 1ull) ? 1 : (((Bb >> lane) & 1ull) ? 0 : -255);
  out[p] = val;
}

extern "C" void kernel_launch(void* const* d_in, const int* in_sizes, int n_in,
                              void* d_out, int out_size, void* d_ws, size_t ws_size,
                              hipStream_t stream) {
  (void)in_sizes; (void)n_in; (void)out_size; (void)ws_size;
  const float* x = (const float*)d_in[0];
  int* out = (int*)d_out;
  char* ws = (char*)d_ws;

  // ---- workspace layout (bytes) ----
  uint32_t* keys  = (uint32_t*)(ws + 0);        // 128*4 u32
  uint32_t* kbg   = (uint32_t*)(ws + 2048);     // 128
  int*      th    = (int*)     (ws + 2560);     // 128
  uint32_t* b1_fg = (uint32_t*)(ws + 3072);
  uint32_t* r1_fg = (uint32_t*)(ws + 3584);
  uint32_t* b1_bg = (uint32_t*)(ws + 4096);
  uint32_t* r1_bg = (uint32_t*)(ws + 4608);
  uint32_t* b1_be = (uint32_t*)(ws + 5120);
  uint32_t* r1_be = (uint32_t*)(ws + 5632);
  uint64_t* cut_fg = (uint64_t*)(ws + 6144);    // 128 u64
  uint64_t* cut_bg = (uint64_t*)(ws + 7168);
  uint64_t* cut_be = (uint64_t*)(ws + 8192);
  // zeroed region [16384, 16384+6424576)
  char* Z = ws + 16384;
  uint32_t* Efg    = (uint32_t*)(Z + 0);        // 512 B
  uint32_t* cnt_fg = (uint32_t*)(Z + 512);
  uint32_t* cnt_bg = (uint32_t*)(Z + 1024);
  uint32_t* cnt_be = (uint32_t*)(Z + 1536);
  uint32_t* gh256  = (uint32_t*)(Z + 2048);     // 128*256*4 = 131072
  uint32_t* gh_fg  = (uint32_t*)(Z + 133120);   // 128*4096*4 = 2 MB
  uint32_t* gh_bg  = (uint32_t*)(Z + 2230272);
  uint32_t* gh_be  = (uint32_t*)(Z + 4327424);
  size_t Zsize = 4327424 + 2097152;             // = 6424576
  char* P = Z + Zsize;
  uint64_t* list_fg = (uint64_t*)(P + 0);       // 128*CAP*8 = 1 MB
  uint64_t* list_bg = (uint64_t*)(P + 1048576);
  uint64_t* list_be = (uint64_t*)(P + 2097152);
  uint64_t* bmA = (uint64_t*)(P + 3145728);     // 4 MB each
  uint64_t* bmB = (uint64_t*)(P + 3145728 + 4194304);
  uint64_t* bmC = (uint64_t*)(P + 3145728 + 8388608);

  hipMemsetAsync(Z, 0, Zsize, stream);
  k_keys   <<<1, 128, 0, stream>>>(keys, kbg);
  k_hist256<<<BATCH * 16, 256, 0, stream>>>(x, gh256);
  k_otsu   <<<BATCH, 256, 0, stream>>>(gh256, th);
  k_roi    <<<(BATCH * HW) / 256, 256, 0, stream>>>(x, th, bmA);
  k_rowmin <<<(BATCH * WPI) / 256, 256, 0, stream>>>(bmA, bmB);
  k_colmin <<<(BATCH * WPI) / 256, 256, 0, stream>>>(bmB, bmA);   // eroded ROI in A
  k_count  <<<BATCH, 256, 0, stream>>>(bmA, Efg);
  // fg select: top-1000 by score among eroded ROI  -> bmB
  k_sel_hist   <<<BATCH * 4, 1024, 0, stream>>>(bmA, keys, 0, Efg, gh_fg);
  k_scan_desc  <<<BATCH, 256, 0, stream>>>(gh_fg, Efg, b1_fg, r1_fg);
  k_sel_collect<<<BATCH * 4, 1024, 0, stream>>>(bmA, keys, 0, b1_fg, cnt_fg, list_fg);
  k_cut        <<<BATCH, 1024, 0, stream>>>(b1_fg, r1_fg, cnt_fg, list_fg, cut_fg);
  k_sel_emit   <<<BATCH * 4, 1024, 0, stream>>>(bmA, keys, 0, cut_fg, bmB);
  // bg eligibility: bottom-K floats -> bmC
  k_bg_hist    <<<BATCH * 4, 1024, 0, stream>>>(x, gh_be);
  k_scan_asc   <<<BATCH, 256, 0, stream>>>(gh_be, kbg, b1_be, r1_be);
  k_bg_collect <<<BATCH * 4, 1024, 0, stream>>>(x, b1_be, cnt_be, list_be);
  k_cut        <<<BATCH, 1024, 0, stream>>>(b1_be, r1_be, cnt_be, list_be, cut_be);
  k_bg_emit    <<<BATCH * 4, 1024, 0, stream>>>(x, cut_be, bmC);
  // bg select: top-1000 by score among eligible -> bmA  (E = kbg, always >1000)
  k_sel_hist   <<<BATCH * 4, 1024, 0, stream>>>(bmC, keys, 2, kbg, gh_bg);
  k_scan_desc  <<<BATCH, 256, 0, stream>>>(gh_bg, kbg, b1_bg, r1_bg);
  k_sel_collect<<<BATCH * 4, 1024, 0, stream>>>(bmC, keys, 2, b1_bg, cnt_bg, list_bg);
  k_cut        <<<BATCH, 1024, 0, stream>>>(b1_bg, r1_bg, cnt_bg, list_bg, cut_bg);
  k_sel_emit   <<<BATCH * 4, 1024, 0, stream>>>(bmC, keys, 2, cut_bg, bmA);
  // dilation + compose
  k_rowdil <<<(BATCH * WPI) / 256, 256, 0, stream>>>(bmB, bmC);   // fg row-dil in C
  k_rowdil <<<(BATCH * WPI) / 256, 256, 0, stream>>>(bmA, bmB);   // bg row-dil in B
  k_compose<<<(BATCH * HW) / 256, 256, 0, stream>>>(bmC, bmB, out);
}